// Round 1
// baseline (961.518 us; speedup 1.0000x reference)
//
#include <hip/hip_runtime.h>
#include <math.h>

// ---------------- problem constants ----------------
constexpr int NN  = 32768;   // nodes
constexpr int BG  = 64;      // graphs
constexpr int NPG = 512;     // nodes per graph
constexpr int EG  = 524288;  // edges
constexpr int HH  = 4;       // heads
constexpr int FH  = 64;      // per-head dim
constexpr int CC  = 256;     // H*Fh
constexpr int FIN = 128;
constexpr int KP1 = 256;     // pool1 k
constexpr int KP2 = 128;     // pool2 k

// ---------------- helpers ----------------
__device__ inline void atomicMaxFloat(float* addr, float value) {
    if (value >= 0.0f)
        atomicMax((int*)addr, __float_as_int(value));
    else
        atomicMin((unsigned int*)addr, __float_as_uint(value));
}

__device__ inline float leaky02(float v) { return v > 0.0f ? v : 0.2f * v; }

// ---------------- GEMM: C[M,256] = A[M,K] @ B[K,256], fp32 ----------------
// BM=128, BN=64, BK=16, 256 threads, 8x4 per-thread tile.
__global__ __launch_bounds__(256) void gemm_fp32(const float* __restrict__ A,
                                                 const float* __restrict__ B,
                                                 float* __restrict__ Cm,
                                                 int M, int K, int Nc) {
    __shared__ float As[16][128];
    __shared__ float Bs[16][64];
    const int t  = threadIdx.x;
    const int bm = blockIdx.x * 128;
    const int bn = blockIdx.y * 64;
    const int tx = t & 15;   // 0..15 col group
    const int ty = t >> 4;   // 0..15 row group
    const int ar = t >> 2;          // 0..63
    const int ac = (t & 3) << 2;    // 0,4,8,12
    const int br = t >> 4;          // 0..15
    const int bc = (t & 15) << 2;   // 0..60

    float acc[8][4];
#pragma unroll
    for (int i = 0; i < 8; ++i)
#pragma unroll
        for (int j = 0; j < 4; ++j) acc[i][j] = 0.0f;

    for (int k0 = 0; k0 < K; k0 += 16) {
        float4 a0 = *(const float4*)(A + (size_t)(bm + ar) * K + k0 + ac);
        float4 a1 = *(const float4*)(A + (size_t)(bm + ar + 64) * K + k0 + ac);
        float4 b0 = *(const float4*)(B + (size_t)(k0 + br) * Nc + bn + bc);
        __syncthreads();
        As[ac + 0][ar] = a0.x; As[ac + 1][ar] = a0.y;
        As[ac + 2][ar] = a0.z; As[ac + 3][ar] = a0.w;
        As[ac + 0][ar + 64] = a1.x; As[ac + 1][ar + 64] = a1.y;
        As[ac + 2][ar + 64] = a1.z; As[ac + 3][ar + 64] = a1.w;
        *(float4*)&Bs[br][bc] = b0;
        __syncthreads();
#pragma unroll
        for (int k = 0; k < 16; ++k) {
            float av[8], bv[4];
            *(float4*)(av)     = *(const float4*)&As[k][ty * 8];
            *(float4*)(av + 4) = *(const float4*)&As[k][ty * 8 + 4];
            *(float4*)(bv)     = *(const float4*)&Bs[k][tx * 4];
#pragma unroll
            for (int i = 0; i < 8; ++i)
#pragma unroll
                for (int j = 0; j < 4; ++j)
                    acc[i][j] = fmaf(av[i], bv[j], acc[i][j]);
        }
    }
#pragma unroll
    for (int i = 0; i < 8; ++i) {
        float4 v = make_float4(acc[i][0], acc[i][1], acc[i][2], acc[i][3]);
        *(float4*)(Cm + (size_t)(bm + ty * 8 + i) * Nc + bn + tx * 4) = v;
    }
}

// ---------------- per-node attention coefficients es/ed ----------------
// one wave (64 threads) per node; lane l handles channels 4l..4l+3
__global__ __launch_bounds__(64) void attn_coeff(const float* __restrict__ z,
                                                 const float* __restrict__ a_src,
                                                 const float* __restrict__ a_dst,
                                                 float* __restrict__ es,
                                                 float* __restrict__ ed) {
    const int node = blockIdx.x;
    const int l = threadIdx.x;
    float4 zr = *(const float4*)(z + (size_t)node * CC + l * 4);
    float4 as = *(const float4*)(a_src + l * 4);
    float4 ad = *(const float4*)(a_dst + l * 4);
    float ps = zr.x * as.x + zr.y * as.y + zr.z * as.z + zr.w * as.w;
    float pd = zr.x * ad.x + zr.y * ad.y + zr.z * ad.z + zr.w * ad.w;
    // reduce within groups of 16 lanes (one head per group)
    for (int o = 8; o >= 1; o >>= 1) {
        ps += __shfl_down(ps, o, 16);
        pd += __shfl_down(pd, o, 16);
    }
    if ((l & 15) == 0) {
        es[node * HH + (l >> 4)] = ps;
        ed[node * HH + (l >> 4)] = pd;
    }
}

// ---------------- init kernels ----------------
__global__ void init_mden(float* m, float* den) {
    int i = blockIdx.x * 256 + threadIdx.x;
    if (i < NN * HH) { ((unsigned int*)m)[i] = 0xFF800000u; den[i] = 0.0f; }
}
__global__ void init_cnt(int* cnt) {
    int i = blockIdx.x * 256 + threadIdx.x;
    if (i < NN) cnt[i] = 0;
}

// ---------------- CSR build (by dst) ----------------
__global__ void csr_hist(const int* __restrict__ dst, int* cnt) {
    int e = blockIdx.x * 256 + threadIdx.x;
    if (e < EG) atomicAdd(&cnt[dst[e]], 1);
}
__global__ __launch_bounds__(1024) void csr_scan(const int* __restrict__ cnt,
                                                 int* __restrict__ rowp,
                                                 int* __restrict__ cur) {
    __shared__ int tmp[1024];
    const int t = threadIdx.x;
    const int base = t * 32;
    int local[32];
    int s = 0;
#pragma unroll
    for (int i = 0; i < 32; ++i) { local[i] = s; s += cnt[base + i]; }
    tmp[t] = s;
    __syncthreads();
    for (int o = 1; o < 1024; o <<= 1) {
        int v = (t >= o) ? tmp[t - o] : 0;
        __syncthreads();
        tmp[t] += v;
        __syncthreads();
    }
    int off = tmp[t] - s;  // exclusive prefix
#pragma unroll
    for (int i = 0; i < 32; ++i) {
        int p = off + local[i];
        rowp[base + i] = p;
        cur[base + i] = p;
    }
    if (t == 1023) rowp[NN] = off + s;
}
__global__ void csr_scatter(const int* __restrict__ src, const int* __restrict__ dst,
                            int* cur, int* __restrict__ esrc) {
    int e = blockIdx.x * 256 + threadIdx.x;
    if (e < EG) {
        int p = atomicAdd(&cur[dst[e]], 1);
        esrc[p] = src[e];
    }
}

// ---------------- edge softmax: max and exp-sum passes ----------------
__global__ void edge_max(const int* __restrict__ src, const int* __restrict__ dst,
                         const float* __restrict__ es, const float* __restrict__ ed,
                         float* m) {
    int e = blockIdx.x * 256 + threadIdx.x;
    if (e >= EG + NN) return;
    int s, d;
    if (e < EG) { s = src[e]; d = dst[e]; } else { s = d = e - EG; }
#pragma unroll
    for (int h = 0; h < HH; ++h) {
        float v = leaky02(es[s * HH + h] + ed[d * HH + h]);
        atomicMaxFloat(&m[d * HH + h], v);
    }
}
__global__ void edge_expsum(const int* __restrict__ src, const int* __restrict__ dst,
                            const float* __restrict__ es, const float* __restrict__ ed,
                            const float* __restrict__ m, float* den) {
    int e = blockIdx.x * 256 + threadIdx.x;
    if (e >= EG + NN) return;
    int s, d;
    if (e < EG) { s = src[e]; d = dst[e]; } else { s = d = e - EG; }
#pragma unroll
    for (int h = 0; h < HH; ++h) {
        float v = leaky02(es[s * HH + h] + ed[d * HH + h]);
        atomicAdd(&den[d * HH + h], __expf(v - m[d * HH + h]));
    }
}

// ---------------- aggregation: out[d] = sum alpha * z[s], + bias, ELU -------
// one block (256 threads) per dst node; thread t = channel t, head t/64
__global__ __launch_bounds__(256) void aggregate(const float* __restrict__ z,
                                                 const int* __restrict__ rowp,
                                                 const int* __restrict__ esrc,
                                                 const float* __restrict__ es,
                                                 const float* __restrict__ ed,
                                                 const float* __restrict__ m,
                                                 const float* __restrict__ den,
                                                 const float* __restrict__ bias,
                                                 float* __restrict__ out) {
    const int d = blockIdx.x;
    const int t = threadIdx.x;
    const int h = t >> 6;
    const float mh  = m[d * HH + h];
    const float dh  = den[d * HH + h] + 1e-16f;
    const float edh = ed[d * HH + h];
    float acc = 0.0f;
    const int beg = rowp[d], end = rowp[d + 1];
    for (int p = beg; p < end; ++p) {
        int s = esrc[p];
        float v = leaky02(es[s * HH + h] + edh);
        float alpha = __expf(v - mh) / dh;
        acc += alpha * z[(size_t)s * CC + t];
    }
    { // self loop
        float v = leaky02(es[d * HH + h] + edh);
        float alpha = __expf(v - mh) / dh;
        acc += alpha * z[(size_t)d * CC + t];
    }
    float o = acc + bias[t];
    out[(size_t)d * CC + t] = o > 0.0f ? o : expm1f(o);  // ELU
}

// ---------------- fused pool2 score weights: w12 = p1_tw @ p2_sw ----------
__global__ __launch_bounds__(256) void fuse_w12(const float* __restrict__ tw1,
                                                const float* __restrict__ sw2,
                                                const float* __restrict__ tb1,
                                                const float* __restrict__ sb2,
                                                float* __restrict__ w12,
                                                float* __restrict__ b12) {
    int j = threadIdx.x;
    float s = 0.0f;
    for (int o = 0; o < CC; ++o) s += tw1[j * CC + o] * sw2[o];
    w12[j] = s;
    if (j == 0) {
        float b = 0.0f;
        for (int o = 0; o < CC; ++o) b += tb1[o] * sw2[o];
        *b12 = b + sb2[0];
    }
}

// ---------------- node scores (logits; sigmoid is monotone) ---------------
__global__ __launch_bounds__(64) void scores_k(const float* __restrict__ h2,
                                               const float* __restrict__ sw1,
                                               const float* __restrict__ sb1,
                                               const float* __restrict__ w12,
                                               const float* __restrict__ b12,
                                               float* __restrict__ sc1,
                                               float* __restrict__ sc2) {
    const int node = blockIdx.x;
    const int l = threadIdx.x;
    float4 hv = *(const float4*)(h2 + (size_t)node * CC + l * 4);
    float4 w1 = *(const float4*)(sw1 + l * 4);
    float4 w2 = *(const float4*)(w12 + l * 4);
    float p1 = hv.x * w1.x + hv.y * w1.y + hv.z * w1.z + hv.w * w1.w;
    float p2 = hv.x * w2.x + hv.y * w2.y + hv.z * w2.z + hv.w * w2.w;
    for (int o = 32; o >= 1; o >>= 1) {
        p1 += __shfl_down(p1, o);
        p2 += __shfl_down(p2, o);
    }
    if (l == 0) {
        sc1[node] = p1 + sb1[0];
        sc2[node] = p2 + b12[0];
    }
}

// ---------------- per-graph top-k selection by rank counting --------------
// matches lax.top_k sets (lower index wins ties). mask==nullptr -> all valid.
__global__ __launch_bounds__(512) void topk_select(const float* __restrict__ sc,
                                                   const int* __restrict__ mask,
                                                   int* __restrict__ sel, int k) {
    __shared__ float s[NPG];
    const int g = blockIdx.x;
    const int i = threadIdx.x;
    const int gi = g * NPG + i;
    float v = sc[gi];
    if (mask && !mask[gi]) v = -INFINITY;
    s[i] = v;
    __syncthreads();
    int rank = 0;
    for (int j = 0; j < NPG; ++j) {
        float sj = s[j];
        if (sj > v || (sj == v && j < i)) rank++;
    }
    int ok = (rank < k);
    if (mask && !mask[gi]) ok = 0;
    sel[gi] = ok;
}

// ---------------- per-graph mean over selected nodes ----------------------
__global__ __launch_bounds__(256) void graph_mean(const float* __restrict__ h2,
                                                  const int* __restrict__ sel,
                                                  float* __restrict__ mg) {
    const int g = blockIdx.x;
    const int t = threadIdx.x;
    float s = 0.0f;
    for (int i = 0; i < NPG; ++i) {
        if (sel[g * NPG + i]) s += h2[(size_t)(g * NPG + i) * CC + t];
    }
    mg[g * CC + t] = s * (1.0f / KP2);
}

// ---------------- classifier head (per graph) -----------------------------
__global__ __launch_bounds__(256) void head_k(const float* __restrict__ mg,
                                              const float* __restrict__ tw1,
                                              const float* __restrict__ tb1,
                                              const float* __restrict__ tw2,
                                              const float* __restrict__ tb2,
                                              const float* __restrict__ c1w,
                                              const float* __restrict__ c1b,
                                              const float* __restrict__ c2w,
                                              const float* __restrict__ c2b,
                                              float* __restrict__ out) {
    __shared__ float v0[CC], v1[CC], v2[64];
    const int g = blockIdx.x;
    const int t = threadIdx.x;
    v0[t] = mg[g * CC + t];
    __syncthreads();
    float s = tb1[t];
    for (int j = 0; j < CC; ++j) s = fmaf(v0[j], tw1[j * CC + t], s);
    v1[t] = s;
    __syncthreads();
    s = tb2[t];
    for (int j = 0; j < CC; ++j) s = fmaf(v1[j], tw2[j * CC + t], s);
    v0[t] = s;
    __syncthreads();
    if (t < 64) {
        float u = c1b[t];
        for (int j = 0; j < CC; ++j) u = fmaf(v0[j], c1w[j * 64 + t], u);
        v2[t] = fmaxf(u, 0.0f);
    }
    __syncthreads();
    if (t < 2) {
        float o = c2b[t];
        for (int j = 0; j < 64; ++j) o = fmaf(v2[j], c2w[j * 2 + t], o);
        v1[t] = o;
    }
    __syncthreads();
    if (t == 0) {
        float a = v1[0], b = v1[1];
        float mx = fmaxf(a, b);
        float lse = mx + logf(expf(a - mx) + expf(b - mx));
        out[g * 2 + 0] = a - lse;
        out[g * 2 + 1] = b - lse;
    }
}

// ---------------- launcher ----------------
extern "C" void kernel_launch(void* const* d_in, const int* in_sizes, int n_in,
                              void* d_out, int out_size, void* d_ws, size_t ws_size,
                              hipStream_t stream) {
    const float* x      = (const float*)d_in[0];
    const int*   ei     = (const int*)d_in[1];
    const int*   src    = ei;
    const int*   dst    = ei + EG;
    const float* W1     = (const float*)d_in[3];
    const float* a_src1 = (const float*)d_in[4];
    const float* a_dst1 = (const float*)d_in[5];
    const float* b1     = (const float*)d_in[6];
    const float* W2     = (const float*)d_in[7];
    const float* a_src2 = (const float*)d_in[8];
    const float* a_dst2 = (const float*)d_in[9];
    const float* b2     = (const float*)d_in[10];
    const float* p1_sw  = (const float*)d_in[11];
    const float* p1_sb  = (const float*)d_in[12];
    const float* p1_tw  = (const float*)d_in[13];
    const float* p1_tb  = (const float*)d_in[14];
    const float* p2_sw  = (const float*)d_in[15];
    const float* p2_sb  = (const float*)d_in[16];
    const float* p2_tw  = (const float*)d_in[17];
    const float* p2_tb  = (const float*)d_in[18];
    const float* c1w    = (const float*)d_in[19];
    const float* c1b    = (const float*)d_in[20];
    const float* c2w    = (const float*)d_in[21];
    const float* c2b    = (const float*)d_in[22];
    float* out = (float*)d_out;

    // workspace layout (floats)
    float* ws   = (float*)d_ws;
    float* z    = ws;                       // N*C
    float* feat = z + (size_t)NN * CC;      // N*C (h1 then h2)
    float* es   = feat + (size_t)NN * CC;   // N*H
    float* ed   = es + NN * HH;
    float* m    = ed + NN * HH;
    float* den  = m + NN * HH;
    int*   cnt  = (int*)(den + NN * HH);    // N
    int*   rowp = cnt + NN;                 // N+1
    int*   cur  = rowp + NN + 1;            // N
    int*   esrc = cur + NN;                 // E
    float* sc1  = (float*)(esrc + EG);      // N
    float* sc2  = sc1 + NN;                 // N
    int*   sel1 = (int*)(sc2 + NN);         // N
    int*   sel2 = sel1 + NN;                // N
    float* w12  = (float*)(sel2 + NN);      // C
    float* b12  = w12 + CC;                 // 1 (padded)
    float* mg   = b12 + 64;                 // B*C

    // ---- CSR build (dst-grouped), once ----
    init_cnt<<<(NN + 255) / 256, 256, 0, stream>>>(cnt);
    csr_hist<<<(EG + 255) / 256, 256, 0, stream>>>(dst, cnt);
    csr_scan<<<1, 1024, 0, stream>>>(cnt, rowp, cur);
    csr_scatter<<<(EG + 255) / 256, 256, 0, stream>>>(src, dst, cur, esrc);

    dim3 gemm_grid(NN / 128, CC / 64);
    int edge_blocks = (EG + NN + 255) / 256;

    // ---- GAT layer 1 ----
    gemm_fp32<<<gemm_grid, 256, 0, stream>>>(x, W1, z, NN, FIN, CC);
    attn_coeff<<<NN, 64, 0, stream>>>(z, a_src1, a_dst1, es, ed);
    init_mden<<<(NN * HH + 255) / 256, 256, 0, stream>>>(m, den);
    edge_max<<<edge_blocks, 256, 0, stream>>>(src, dst, es, ed, m);
    edge_expsum<<<edge_blocks, 256, 0, stream>>>(src, dst, es, ed, m, den);
    aggregate<<<NN, 256, 0, stream>>>(z, rowp, esrc, es, ed, m, den, b1, feat);

    // ---- GAT layer 2 (z buffer reused; h2 overwrites h1 after gemm) ----
    gemm_fp32<<<gemm_grid, 256, 0, stream>>>(feat, W2, z, NN, CC, CC);
    attn_coeff<<<NN, 64, 0, stream>>>(z, a_src2, a_dst2, es, ed);
    init_mden<<<(NN * HH + 255) / 256, 256, 0, stream>>>(m, den);
    edge_max<<<edge_blocks, 256, 0, stream>>>(src, dst, es, ed, m);
    edge_expsum<<<edge_blocks, 256, 0, stream>>>(src, dst, es, ed, m, den);
    aggregate<<<NN, 256, 0, stream>>>(z, rowp, esrc, es, ed, m, den, b2, feat);

    // ---- pooling + head ----
    fuse_w12<<<1, 256, 0, stream>>>(p1_tw, p2_sw, p1_tb, p2_sb, w12, b12);
    scores_k<<<NN, 64, 0, stream>>>(feat, p1_sw, p1_sb, w12, b12, sc1, sc2);
    topk_select<<<BG, NPG, 0, stream>>>(sc1, nullptr, sel1, KP1);
    topk_select<<<BG, NPG, 0, stream>>>(sc2, sel1, sel2, KP2);
    graph_mean<<<BG, 256, 0, stream>>>(feat, sel2, mg);
    head_k<<<BG, 256, 0, stream>>>(mg, p1_tw, p1_tb, p2_tw, p2_tb,
                                   c1w, c1b, c2w, c2b, out);
}

// Round 2
// 543.663 us; speedup vs baseline: 1.7686x; 1.7686x over previous
//
#include <hip/hip_runtime.h>
#include <math.h>

// ---------------- problem constants ----------------
constexpr int NN  = 32768;   // nodes
constexpr int BG  = 64;      // graphs
constexpr int NPG = 512;     // nodes per graph
constexpr int EG  = 524288;  // edges
constexpr int HH  = 4;       // heads
constexpr int FH  = 64;      // per-head dim
constexpr int CC  = 256;     // H*Fh
constexpr int FIN = 128;
constexpr int KP1 = 256;     // pool1 k
constexpr int KP2 = 128;     // pool2 k

__device__ inline float leaky02(float v) { return v > 0.0f ? v : 0.2f * v; }

// ---------------- GEMM: C[M,256] = A[M,K] @ B[K,256], fp32 ----------------
// BM=128, BN=64, BK=16, 256 threads, 8x4 per-thread tile.
__global__ __launch_bounds__(256) void gemm_fp32(const float* __restrict__ A,
                                                 const float* __restrict__ B,
                                                 float* __restrict__ Cm,
                                                 int M, int K, int Nc) {
    __shared__ float As[16][128];
    __shared__ float Bs[16][64];
    const int t  = threadIdx.x;
    const int bm = blockIdx.x * 128;
    const int bn = blockIdx.y * 64;
    const int tx = t & 15;   // 0..15 col group
    const int ty = t >> 4;   // 0..15 row group
    const int ar = t >> 2;          // 0..63
    const int ac = (t & 3) << 2;    // 0,4,8,12
    const int br = t >> 4;          // 0..15
    const int bc = (t & 15) << 2;   // 0..60

    float acc[8][4];
#pragma unroll
    for (int i = 0; i < 8; ++i)
#pragma unroll
        for (int j = 0; j < 4; ++j) acc[i][j] = 0.0f;

    for (int k0 = 0; k0 < K; k0 += 16) {
        float4 a0 = *(const float4*)(A + (size_t)(bm + ar) * K + k0 + ac);
        float4 a1 = *(const float4*)(A + (size_t)(bm + ar + 64) * K + k0 + ac);
        float4 b0 = *(const float4*)(B + (size_t)(k0 + br) * Nc + bn + bc);
        __syncthreads();
        As[ac + 0][ar] = a0.x; As[ac + 1][ar] = a0.y;
        As[ac + 2][ar] = a0.z; As[ac + 3][ar] = a0.w;
        As[ac + 0][ar + 64] = a1.x; As[ac + 1][ar + 64] = a1.y;
        As[ac + 2][ar + 64] = a1.z; As[ac + 3][ar + 64] = a1.w;
        *(float4*)&Bs[br][bc] = b0;
        __syncthreads();
#pragma unroll
        for (int k = 0; k < 16; ++k) {
            float av[8], bv[4];
            *(float4*)(av)     = *(const float4*)&As[k][ty * 8];
            *(float4*)(av + 4) = *(const float4*)&As[k][ty * 8 + 4];
            *(float4*)(bv)     = *(const float4*)&Bs[k][tx * 4];
#pragma unroll
            for (int i = 0; i < 8; ++i)
#pragma unroll
                for (int j = 0; j < 4; ++j)
                    acc[i][j] = fmaf(av[i], bv[j], acc[i][j]);
        }
    }
#pragma unroll
    for (int i = 0; i < 8; ++i) {
        float4 v = make_float4(acc[i][0], acc[i][1], acc[i][2], acc[i][3]);
        *(float4*)(Cm + (size_t)(bm + ty * 8 + i) * Nc + bn + tx * 4) = v;
    }
}

// ---------------- per-node attention coefficients es/ed ----------------
__global__ __launch_bounds__(64) void attn_coeff(const float* __restrict__ z,
                                                 const float* __restrict__ a_src,
                                                 const float* __restrict__ a_dst,
                                                 float* __restrict__ es,
                                                 float* __restrict__ ed) {
    const int node = blockIdx.x;
    const int l = threadIdx.x;
    float4 zr = *(const float4*)(z + (size_t)node * CC + l * 4);
    float4 as = *(const float4*)(a_src + l * 4);
    float4 ad = *(const float4*)(a_dst + l * 4);
    float ps = zr.x * as.x + zr.y * as.y + zr.z * as.z + zr.w * as.w;
    float pd = zr.x * ad.x + zr.y * ad.y + zr.z * ad.z + zr.w * ad.w;
    for (int o = 8; o >= 1; o >>= 1) {
        ps += __shfl_down(ps, o, 16);
        pd += __shfl_down(pd, o, 16);
    }
    if ((l & 15) == 0) {
        es[node * HH + (l >> 4)] = ps;
        ed[node * HH + (l >> 4)] = pd;
    }
}

// ---------------- init / CSR build (by dst) ----------------
__global__ void init_cnt(int* cnt) {
    int i = blockIdx.x * 256 + threadIdx.x;
    if (i < NN) cnt[i] = 0;
}
__global__ void csr_hist(const int* __restrict__ dst, int* cnt) {
    int e = blockIdx.x * 256 + threadIdx.x;
    if (e < EG) atomicAdd(&cnt[dst[e]], 1);
}
__global__ __launch_bounds__(1024) void csr_scan(const int* __restrict__ cnt,
                                                 int* __restrict__ rowp,
                                                 int* __restrict__ cur) {
    __shared__ int tmp[1024];
    const int t = threadIdx.x;
    const int base = t * 32;
    int local[32];
    int s = 0;
#pragma unroll
    for (int i = 0; i < 32; ++i) { local[i] = s; s += cnt[base + i]; }
    tmp[t] = s;
    __syncthreads();
    for (int o = 1; o < 1024; o <<= 1) {
        int v = (t >= o) ? tmp[t - o] : 0;
        __syncthreads();
        tmp[t] += v;
        __syncthreads();
    }
    int off = tmp[t] - s;  // exclusive prefix
#pragma unroll
    for (int i = 0; i < 32; ++i) {
        int p = off + local[i];
        rowp[base + i] = p;
        cur[base + i] = p;
    }
    if (t == 1023) rowp[NN] = off + s;
}
__global__ void csr_scatter(const int* __restrict__ src, const int* __restrict__ dst,
                            int* cur, int* __restrict__ esrc) {
    int e = blockIdx.x * 256 + threadIdx.x;
    if (e < EG) {
        int p = atomicAdd(&cur[dst[e]], 1);
        esrc[p] = src[e];
    }
}

// ---------------- per-node edge softmax over dst-CSR, no atomics ----------
// one wave per node; lane l: head h = l&3, edge-slot ei = l>>2 (16 slots).
// writes normalized alpha into ex[csr_pos*4+h] and exself[d*4+h].
__global__ __launch_bounds__(64) void softmax_csr(const int* __restrict__ rowp,
                                                  const int* __restrict__ esrc,
                                                  const float* __restrict__ es,
                                                  const float* __restrict__ ed,
                                                  float* __restrict__ ex,
                                                  float* __restrict__ exself) {
    const int d  = blockIdx.x;
    const int l  = threadIdx.x;
    const int h  = l & 3;
    const int ei = l >> 2;
    const float edh = ed[d * HH + h];
    const int beg = rowp[d];
    const int deg = rowp[d + 1] - beg;

    float vmax = -INFINITY;
    float vself = 0.0f;
    if (ei == 0) {
        vself = leaky02(es[d * HH + h] + edh);
        vmax = vself;
    }
    for (int i = ei; i < deg; i += 16) {
        int s = esrc[beg + i];
        float v = leaky02(es[s * HH + h] + edh);
        ex[(size_t)(beg + i) * HH + h] = v;
        vmax = fmaxf(vmax, v);
    }
#pragma unroll
    for (int o = 4; o <= 32; o <<= 1) vmax = fmaxf(vmax, __shfl_xor(vmax, o));

    float dsum = 0.0f;
    for (int i = ei; i < deg; i += 16) {
        float e = __expf(ex[(size_t)(beg + i) * HH + h] - vmax);
        ex[(size_t)(beg + i) * HH + h] = e;
        dsum += e;
    }
    float eself = 0.0f;
    if (ei == 0) { eself = __expf(vself - vmax); dsum += eself; }
#pragma unroll
    for (int o = 4; o <= 32; o <<= 1) dsum += __shfl_xor(dsum, o);
    const float inv = 1.0f / (dsum + 1e-16f);

    for (int i = ei; i < deg; i += 16)
        ex[(size_t)(beg + i) * HH + h] *= inv;
    if (ei == 0) exself[d * HH + h] = eself * inv;
}

// ---------------- aggregation: out[d] = sum alpha * z[s], + bias, ELU ------
// one block (256 threads) per dst node; thread t = channel t, head t>>6.
__global__ __launch_bounds__(256) void aggregate(const float* __restrict__ z,
                                                 const int* __restrict__ rowp,
                                                 const int* __restrict__ esrc,
                                                 const float* __restrict__ ex,
                                                 const float* __restrict__ exself,
                                                 const float* __restrict__ bias,
                                                 float* __restrict__ out) {
    __shared__ int   s_idx[64];
    __shared__ float s_a[256];   // alpha for 64 edges x 4 heads, csr layout
    const int d = blockIdx.x;
    const int t = threadIdx.x;
    const int h = t >> 6;
    const int beg = rowp[d];
    const int deg = rowp[d + 1] - beg;

    float acc = exself[d * HH + h] * z[(size_t)d * CC + t];
    for (int base = 0; base < deg; base += 64) {
        const int n = min(64, deg - base);
        if (t < n) s_idx[t] = esrc[beg + base + t];
        if (t < n * HH) s_a[t] = ex[(size_t)(beg + base) * HH + t];
        __syncthreads();
        for (int i = 0; i < n; ++i) {
            int s = s_idx[i];
            acc = fmaf(s_a[i * HH + h], z[(size_t)s * CC + t], acc);
        }
        __syncthreads();
    }
    float o = acc + bias[t];
    out[(size_t)d * CC + t] = o > 0.0f ? o : expm1f(o);  // ELU
}

// ---------------- fused pool2 score weights: w12 = p1_tw @ p2_sw ----------
__global__ __launch_bounds__(256) void fuse_w12(const float* __restrict__ tw1,
                                                const float* __restrict__ sw2,
                                                const float* __restrict__ tb1,
                                                const float* __restrict__ sb2,
                                                float* __restrict__ w12,
                                                float* __restrict__ b12) {
    int j = threadIdx.x;
    float s = 0.0f;
    for (int o = 0; o < CC; ++o) s += tw1[j * CC + o] * sw2[o];
    w12[j] = s;
    if (j == 0) {
        float b = 0.0f;
        for (int o = 0; o < CC; ++o) b += tb1[o] * sw2[o];
        *b12 = b + sb2[0];
    }
}

// ---------------- node scores (logits; sigmoid is monotone) ---------------
__global__ __launch_bounds__(64) void scores_k(const float* __restrict__ h2,
                                               const float* __restrict__ sw1,
                                               const float* __restrict__ sb1,
                                               const float* __restrict__ w12,
                                               const float* __restrict__ b12,
                                               float* __restrict__ sc1,
                                               float* __restrict__ sc2) {
    const int node = blockIdx.x;
    const int l = threadIdx.x;
    float4 hv = *(const float4*)(h2 + (size_t)node * CC + l * 4);
    float4 w1 = *(const float4*)(sw1 + l * 4);
    float4 w2 = *(const float4*)(w12 + l * 4);
    float p1 = hv.x * w1.x + hv.y * w1.y + hv.z * w1.z + hv.w * w1.w;
    float p2 = hv.x * w2.x + hv.y * w2.y + hv.z * w2.z + hv.w * w2.w;
    for (int o = 32; o >= 1; o >>= 1) {
        p1 += __shfl_down(p1, o);
        p2 += __shfl_down(p2, o);
    }
    if (l == 0) {
        sc1[node] = p1 + sb1[0];
        sc2[node] = p2 + b12[0];
    }
}

// ---------------- per-graph top-k selection by rank counting --------------
__global__ __launch_bounds__(512) void topk_select(const float* __restrict__ sc,
                                                   const int* __restrict__ mask,
                                                   int* __restrict__ sel, int k) {
    __shared__ float s[NPG];
    const int g = blockIdx.x;
    const int i = threadIdx.x;
    const int gi = g * NPG + i;
    float v = sc[gi];
    if (mask && !mask[gi]) v = -INFINITY;
    s[i] = v;
    __syncthreads();
    int rank = 0;
    for (int j = 0; j < NPG; ++j) {
        float sj = s[j];
        if (sj > v || (sj == v && j < i)) rank++;
    }
    int ok = (rank < k);
    if (mask && !mask[gi]) ok = 0;
    sel[gi] = ok;
}

// ---------------- per-graph mean over selected nodes ----------------------
__global__ __launch_bounds__(256) void graph_mean(const float* __restrict__ h2,
                                                  const int* __restrict__ sel,
                                                  float* __restrict__ mg) {
    const int g = blockIdx.x;
    const int t = threadIdx.x;
    float s = 0.0f;
    for (int i = 0; i < NPG; ++i) {
        if (sel[g * NPG + i]) s += h2[(size_t)(g * NPG + i) * CC + t];
    }
    mg[g * CC + t] = s * (1.0f / KP2);
}

// ---------------- classifier head (per graph) -----------------------------
__global__ __launch_bounds__(256) void head_k(const float* __restrict__ mg,
                                              const float* __restrict__ tw1,
                                              const float* __restrict__ tb1,
                                              const float* __restrict__ tw2,
                                              const float* __restrict__ tb2,
                                              const float* __restrict__ c1w,
                                              const float* __restrict__ c1b,
                                              const float* __restrict__ c2w,
                                              const float* __restrict__ c2b,
                                              float* __restrict__ out) {
    __shared__ float v0[CC], v1[CC], v2[64];
    const int g = blockIdx.x;
    const int t = threadIdx.x;
    v0[t] = mg[g * CC + t];
    __syncthreads();
    float s = tb1[t];
    for (int j = 0; j < CC; ++j) s = fmaf(v0[j], tw1[j * CC + t], s);
    v1[t] = s;
    __syncthreads();
    s = tb2[t];
    for (int j = 0; j < CC; ++j) s = fmaf(v1[j], tw2[j * CC + t], s);
    v0[t] = s;
    __syncthreads();
    if (t < 64) {
        float u = c1b[t];
        for (int j = 0; j < CC; ++j) u = fmaf(v0[j], c1w[j * 64 + t], u);
        v2[t] = fmaxf(u, 0.0f);
    }
    __syncthreads();
    if (t < 2) {
        float o = c2b[t];
        for (int j = 0; j < 64; ++j) o = fmaf(v2[j], c2w[j * 2 + t], o);
        v1[t] = o;
    }
    __syncthreads();
    if (t == 0) {
        float a = v1[0], b = v1[1];
        float mx = fmaxf(a, b);
        float lse = mx + logf(expf(a - mx) + expf(b - mx));
        out[g * 2 + 0] = a - lse;
        out[g * 2 + 1] = b - lse;
    }
}

// ---------------- launcher ----------------
extern "C" void kernel_launch(void* const* d_in, const int* in_sizes, int n_in,
                              void* d_out, int out_size, void* d_ws, size_t ws_size,
                              hipStream_t stream) {
    const float* x      = (const float*)d_in[0];
    const int*   ei     = (const int*)d_in[1];
    const int*   src    = ei;
    const int*   dst    = ei + EG;
    const float* W1     = (const float*)d_in[3];
    const float* a_src1 = (const float*)d_in[4];
    const float* a_dst1 = (const float*)d_in[5];
    const float* b1     = (const float*)d_in[6];
    const float* W2     = (const float*)d_in[7];
    const float* a_src2 = (const float*)d_in[8];
    const float* a_dst2 = (const float*)d_in[9];
    const float* b2     = (const float*)d_in[10];
    const float* p1_sw  = (const float*)d_in[11];
    const float* p1_sb  = (const float*)d_in[12];
    const float* p1_tw  = (const float*)d_in[13];
    const float* p1_tb  = (const float*)d_in[14];
    const float* p2_sw  = (const float*)d_in[15];
    const float* p2_sb  = (const float*)d_in[16];
    const float* p2_tw  = (const float*)d_in[17];
    const float* p2_tb  = (const float*)d_in[18];
    const float* c1w    = (const float*)d_in[19];
    const float* c1b    = (const float*)d_in[20];
    const float* c2w    = (const float*)d_in[21];
    const float* c2b    = (const float*)d_in[22];
    float* out = (float*)d_out;

    // workspace layout (floats)
    float* ws     = (float*)d_ws;
    float* z      = ws;                        // N*C
    float* feat   = z + (size_t)NN * CC;       // N*C
    float* es     = feat + (size_t)NN * CC;    // N*H
    float* ed     = es + NN * HH;              // N*H
    float* exself = ed + NN * HH;              // N*H
    float* ex     = exself + NN * HH;          // E*H
    int*   cnt    = (int*)(ex + (size_t)EG * HH);  // N
    int*   rowp   = cnt + NN;                  // N+1
    int*   cur    = rowp + NN + 1;             // N
    int*   esrc   = cur + NN;                  // E
    float* sc1    = (float*)(esrc + EG);       // N
    float* sc2    = sc1 + NN;                  // N
    int*   sel1   = (int*)(sc2 + NN);          // N
    int*   sel2   = sel1 + NN;                 // N
    float* w12    = (float*)(sel2 + NN);       // C
    float* b12    = w12 + CC;                  // 1 (padded to 64)
    float* mg     = b12 + 64;                  // B*C

    // ---- CSR build (dst-grouped), once ----
    init_cnt<<<(NN + 255) / 256, 256, 0, stream>>>(cnt);
    csr_hist<<<(EG + 255) / 256, 256, 0, stream>>>(dst, cnt);
    csr_scan<<<1, 1024, 0, stream>>>(cnt, rowp, cur);
    csr_scatter<<<(EG + 255) / 256, 256, 0, stream>>>(src, dst, cur, esrc);

    dim3 gemm_grid(NN / 128, CC / 64);

    // ---- GAT layer 1 ----
    gemm_fp32<<<gemm_grid, 256, 0, stream>>>(x, W1, z, NN, FIN, CC);
    attn_coeff<<<NN, 64, 0, stream>>>(z, a_src1, a_dst1, es, ed);
    softmax_csr<<<NN, 64, 0, stream>>>(rowp, esrc, es, ed, ex, exself);
    aggregate<<<NN, 256, 0, stream>>>(z, rowp, esrc, ex, exself, b1, feat);

    // ---- GAT layer 2 ----
    gemm_fp32<<<gemm_grid, 256, 0, stream>>>(feat, W2, z, NN, CC, CC);
    attn_coeff<<<NN, 64, 0, stream>>>(z, a_src2, a_dst2, es, ed);
    softmax_csr<<<NN, 64, 0, stream>>>(rowp, esrc, es, ed, ex, exself);
    aggregate<<<NN, 256, 0, stream>>>(z, rowp, esrc, ex, exself, b2, feat);

    // ---- pooling + head ----
    fuse_w12<<<1, 256, 0, stream>>>(p1_tw, p2_sw, p1_tb, p2_sb, w12, b12);
    scores_k<<<NN, 64, 0, stream>>>(feat, p1_sw, p1_sb, w12, b12, sc1, sc2);
    topk_select<<<BG, NPG, 0, stream>>>(sc1, nullptr, sel1, KP1);
    topk_select<<<BG, NPG, 0, stream>>>(sc2, sel1, sel2, KP2);
    graph_mean<<<BG, 256, 0, stream>>>(feat, sel2, mg);
    head_k<<<BG, 256, 0, stream>>>(mg, p1_tw, p1_tb, p2_tw, p2_tb,
                                   c1w, c1b, c2w, c2b, out);
}

// Round 3
// 498.472 us; speedup vs baseline: 1.9289x; 1.0907x over previous
//
#include <hip/hip_runtime.h>
#include <math.h>

// ---------------- problem constants ----------------
constexpr int NN  = 32768;   // nodes
constexpr int BG  = 64;      // graphs
constexpr int NPG = 512;     // nodes per graph
constexpr int EG  = 524288;  // edges
constexpr int HH  = 4;       // heads
constexpr int FH  = 64;      // per-head dim
constexpr int CC  = 256;     // H*Fh
constexpr int FIN = 128;
constexpr int KP1 = 256;     // pool1 k
constexpr int KP2 = 128;     // pool2 k

__device__ inline float leaky02(float v) { return v > 0.0f ? v : 0.2f * v; }

// XCD-aware node swizzle: graph g -> XCD g&7 so each graph's 512-node tile
// (512 KB of z) stays resident in one XCD's 4 MB L2. 8 graphs per XCD.
__device__ inline int swizzle_node(int b) {
    int xcd  = b & 7;
    int slot = b >> 3;                 // 0..4095
    int g    = xcd + ((slot >> 9) << 3);
    return g * NPG + (slot & (NPG - 1));
}

// ---------------- GEMM: C[M,256] = A[M,K] @ B[K,256], fp32 ----------------
// BM=128, BN=64, BK=16, 256 threads, 8x4 per-thread tile.
// Epilogue (optional): es/ed = per-head dot(h, a_src/a_dst); head = blockIdx.y.
__global__ __launch_bounds__(256) void gemm_fp32_attn(const float* __restrict__ A,
                                                      const float* __restrict__ B,
                                                      float* __restrict__ Cm,
                                                      int M, int K, int Nc,
                                                      const float* __restrict__ a_src,
                                                      const float* __restrict__ a_dst,
                                                      float* __restrict__ es,
                                                      float* __restrict__ ed) {
    __shared__ float As[16][128];
    __shared__ float Bs[16][64];
    const int t  = threadIdx.x;
    const int bm = blockIdx.x * 128;
    const int bn = blockIdx.y * 64;
    const int tx = t & 15;   // 0..15 col group
    const int ty = t >> 4;   // 0..15 row group
    const int ar = t >> 2;          // 0..63
    const int ac = (t & 3) << 2;    // 0,4,8,12
    const int br = t >> 4;          // 0..15
    const int bc = (t & 15) << 2;   // 0..60

    float acc[8][4];
#pragma unroll
    for (int i = 0; i < 8; ++i)
#pragma unroll
        for (int j = 0; j < 4; ++j) acc[i][j] = 0.0f;

    for (int k0 = 0; k0 < K; k0 += 16) {
        float4 a0 = *(const float4*)(A + (size_t)(bm + ar) * K + k0 + ac);
        float4 a1 = *(const float4*)(A + (size_t)(bm + ar + 64) * K + k0 + ac);
        float4 b0 = *(const float4*)(B + (size_t)(k0 + br) * Nc + bn + bc);
        __syncthreads();
        As[ac + 0][ar] = a0.x; As[ac + 1][ar] = a0.y;
        As[ac + 2][ar] = a0.z; As[ac + 3][ar] = a0.w;
        As[ac + 0][ar + 64] = a1.x; As[ac + 1][ar + 64] = a1.y;
        As[ac + 2][ar + 64] = a1.z; As[ac + 3][ar + 64] = a1.w;
        *(float4*)&Bs[br][bc] = b0;
        __syncthreads();
#pragma unroll
        for (int k = 0; k < 16; ++k) {
            float av[8], bv[4];
            *(float4*)(av)     = *(const float4*)&As[k][ty * 8];
            *(float4*)(av + 4) = *(const float4*)&As[k][ty * 8 + 4];
            *(float4*)(bv)     = *(const float4*)&Bs[k][tx * 4];
#pragma unroll
            for (int i = 0; i < 8; ++i)
#pragma unroll
                for (int j = 0; j < 4; ++j)
                    acc[i][j] = fmaf(av[i], bv[j], acc[i][j]);
        }
    }
#pragma unroll
    for (int i = 0; i < 8; ++i) {
        float4 v = make_float4(acc[i][0], acc[i][1], acc[i][2], acc[i][3]);
        *(float4*)(Cm + (size_t)(bm + ty * 8 + i) * Nc + bn + tx * 4) = v;
    }

    if (es) {
        // accumulators hold h for rows bm+ty*8+i, cols bn+tx*4..+3 (one head)
        const float4 as = *(const float4*)(a_src + bn + tx * 4);
        const float4 ad = *(const float4*)(a_dst + bn + tx * 4);
        const int head = blockIdx.y;
#pragma unroll
        for (int i = 0; i < 8; ++i) {
            float ps = acc[i][0] * as.x + acc[i][1] * as.y +
                       acc[i][2] * as.z + acc[i][3] * as.w;
            float pd = acc[i][0] * ad.x + acc[i][1] * ad.y +
                       acc[i][2] * ad.z + acc[i][3] * ad.w;
#pragma unroll
            for (int o = 8; o >= 1; o >>= 1) {
                ps += __shfl_down(ps, o, 16);
                pd += __shfl_down(pd, o, 16);
            }
            if (tx == 0) {
                es[(bm + ty * 8 + i) * HH + head] = ps;
                ed[(bm + ty * 8 + i) * HH + head] = pd;
            }
        }
    }
}

// ---------------- init / CSR build (by dst) ----------------
__global__ void init_cnt(int* cnt) {
    int i = blockIdx.x * 256 + threadIdx.x;
    if (i < NN) cnt[i] = 0;
}
__global__ void csr_hist(const int* __restrict__ dst, int* cnt) {
    int e = blockIdx.x * 256 + threadIdx.x;
    if (e < EG) atomicAdd(&cnt[dst[e]], 1);
}
__global__ __launch_bounds__(1024) void csr_scan(const int* __restrict__ cnt,
                                                 int* __restrict__ rowp,
                                                 int* __restrict__ cur) {
    __shared__ int tmp[1024];
    const int t = threadIdx.x;
    const int base = t * 32;
    int local[32];
    int s = 0;
#pragma unroll
    for (int i = 0; i < 32; ++i) { local[i] = s; s += cnt[base + i]; }
    tmp[t] = s;
    __syncthreads();
    for (int o = 1; o < 1024; o <<= 1) {
        int v = (t >= o) ? tmp[t - o] : 0;
        __syncthreads();
        tmp[t] += v;
        __syncthreads();
    }
    int off = tmp[t] - s;  // exclusive prefix
#pragma unroll
    for (int i = 0; i < 32; ++i) {
        int p = off + local[i];
        rowp[base + i] = p;
        cur[base + i] = p;
    }
    if (t == 1023) rowp[NN] = off + s;
}
__global__ void csr_scatter(const int* __restrict__ src, const int* __restrict__ dst,
                            int* cur, int* __restrict__ esrc) {
    int e = blockIdx.x * 256 + threadIdx.x;
    if (e < EG) {
        int p = atomicAdd(&cur[dst[e]], 1);
        esrc[p] = src[e];
    }
}

// ---------------- per-node edge softmax over dst-CSR, register-resident ----
// one wave per node; lane l: head h = l&3, edge-slot ei = l>>2 (16 slots).
// NS=6 register slots -> supports deg <= 96 fast-path (fixed input max ~40);
// overflow recomputes from L2 (correct for any degree).
__global__ __launch_bounds__(64) void softmax_csr(const int* __restrict__ rowp,
                                                  const int* __restrict__ esrc,
                                                  const float* __restrict__ es,
                                                  const float* __restrict__ ed,
                                                  float* __restrict__ ex,
                                                  float* __restrict__ exself) {
    constexpr int NS = 6;
    const int d  = swizzle_node(blockIdx.x);
    const int l  = threadIdx.x;
    const int h  = l & 3;
    const int ei = l >> 2;
    const float edh = ed[d * HH + h];
    const int beg = rowp[d];
    const int deg = rowp[d + 1] - beg;

    float v[NS];
    float vmax = -INFINITY;
    float vself = 0.0f;
    if (ei == 0) {
        vself = leaky02(es[d * HH + h] + edh);
        vmax = vself;
    }
#pragma unroll
    for (int j = 0; j < NS; ++j) {
        int i = ei + 16 * j;
        if (i < deg) {
            int s = esrc[beg + i];
            v[j] = leaky02(es[s * HH + h] + edh);
            vmax = fmaxf(vmax, v[j]);
        }
    }
    for (int i = ei + 16 * NS; i < deg; i += 16) {     // overflow (never for fixed input)
        int s = esrc[beg + i];
        vmax = fmaxf(vmax, leaky02(es[s * HH + h] + edh));
    }
#pragma unroll
    for (int o = 4; o <= 32; o <<= 1) vmax = fmaxf(vmax, __shfl_xor(vmax, o));

    float dsum = 0.0f;
#pragma unroll
    for (int j = 0; j < NS; ++j) {
        int i = ei + 16 * j;
        if (i < deg) {
            v[j] = __expf(v[j] - vmax);
            dsum += v[j];
        }
    }
    for (int i = ei + 16 * NS; i < deg; i += 16) {
        int s = esrc[beg + i];
        dsum += __expf(leaky02(es[s * HH + h] + edh) - vmax);
    }
    float eself = 0.0f;
    if (ei == 0) { eself = __expf(vself - vmax); dsum += eself; }
#pragma unroll
    for (int o = 4; o <= 32; o <<= 1) dsum += __shfl_xor(dsum, o);
    const float inv = 1.0f / (dsum + 1e-16f);

#pragma unroll
    for (int j = 0; j < NS; ++j) {
        int i = ei + 16 * j;
        if (i < deg) ex[(size_t)(beg + i) * HH + h] = v[j] * inv;
    }
    for (int i = ei + 16 * NS; i < deg; i += 16) {
        int s = esrc[beg + i];
        ex[(size_t)(beg + i) * HH + h] =
            __expf(leaky02(es[s * HH + h] + edh) - vmax) * inv;
    }
    if (ei == 0) exself[d * HH + h] = eself * inv;
}

// ---------------- aggregation: out[d] = sum alpha * z[s], + bias, ELU ------
// one block (256 threads) per dst node (XCD-swizzled); thread t = channel t.
// optional epilogue: pooling score logits sc1/sc2 (layer 2 only).
__global__ __launch_bounds__(256) void aggregate(const float* __restrict__ z,
                                                 const int* __restrict__ rowp,
                                                 const int* __restrict__ esrc,
                                                 const float* __restrict__ ex,
                                                 const float* __restrict__ exself,
                                                 const float* __restrict__ bias,
                                                 float* __restrict__ out,
                                                 const float* __restrict__ sw1,
                                                 const float* __restrict__ sb1,
                                                 const float* __restrict__ w12,
                                                 const float* __restrict__ b12,
                                                 float* __restrict__ sc1,
                                                 float* __restrict__ sc2) {
    __shared__ int   s_idx[64];
    __shared__ float s_a[256];   // alpha for 64 edges x 4 heads, csr layout
    __shared__ float r1[256], r2[256];
    const int d = swizzle_node(blockIdx.x);
    const int t = threadIdx.x;
    const int h = t >> 6;
    const int beg = rowp[d];
    const int deg = rowp[d + 1] - beg;

    float acc = exself[d * HH + h] * z[(size_t)d * CC + t];
    for (int base = 0; base < deg; base += 64) {
        const int n = min(64, deg - base);
        if (t < n) s_idx[t] = esrc[beg + base + t];
        if (t < n * HH) s_a[t] = ex[(size_t)(beg + base) * HH + t];
        __syncthreads();
        for (int i = 0; i < n; ++i) {
            int s = s_idx[i];
            acc = fmaf(s_a[i * HH + h], z[(size_t)s * CC + t], acc);
        }
        __syncthreads();
    }
    float o = acc + bias[t];
    o = o > 0.0f ? o : expm1f(o);  // ELU
    out[(size_t)d * CC + t] = o;

    if (sc1) {
        r1[t] = o * sw1[t];
        r2[t] = o * w12[t];
        __syncthreads();
#pragma unroll
        for (int s = 128; s > 0; s >>= 1) {
            if (t < s) { r1[t] += r1[t + s]; r2[t] += r2[t + s]; }
            __syncthreads();
        }
        if (t == 0) {
            sc1[d] = r1[0] + sb1[0];
            sc2[d] = r2[0] + b12[0];
        }
    }
}

// ---------------- fused pool2 score weights: w12 = p1_tw @ p2_sw ----------
__global__ __launch_bounds__(256) void fuse_w12(const float* __restrict__ tw1,
                                                const float* __restrict__ sw2,
                                                const float* __restrict__ tb1,
                                                const float* __restrict__ sb2,
                                                float* __restrict__ w12,
                                                float* __restrict__ b12) {
    int j = threadIdx.x;
    float s = 0.0f;
    for (int o = 0; o < CC; ++o) s += tw1[j * CC + o] * sw2[o];
    w12[j] = s;
    if (j == 0) {
        float b = 0.0f;
        for (int o = 0; o < CC; ++o) b += tb1[o] * sw2[o];
        *b12 = b + sb2[0];
    }
}

// ---------------- per-graph top-k selection by rank counting --------------
__global__ __launch_bounds__(512) void topk_select(const float* __restrict__ sc,
                                                   const int* __restrict__ mask,
                                                   int* __restrict__ sel, int k) {
    __shared__ float s[NPG];
    const int g = blockIdx.x;
    const int i = threadIdx.x;
    const int gi = g * NPG + i;
    float v = sc[gi];
    if (mask && !mask[gi]) v = -INFINITY;
    s[i] = v;
    __syncthreads();
    int rank = 0;
    for (int j = 0; j < NPG; ++j) {
        float sj = s[j];
        if (sj > v || (sj == v && j < i)) rank++;
    }
    int ok = (rank < k);
    if (mask && !mask[gi]) ok = 0;
    sel[gi] = ok;
}

// ---------------- per-graph mean over selected nodes ----------------------
__global__ __launch_bounds__(256) void graph_mean(const float* __restrict__ h2,
                                                  const int* __restrict__ sel,
                                                  float* __restrict__ mg) {
    const int g = blockIdx.x;
    const int t = threadIdx.x;
    float s = 0.0f;
    for (int i = 0; i < NPG; ++i) {
        if (sel[g * NPG + i]) s += h2[(size_t)(g * NPG + i) * CC + t];
    }
    mg[g * CC + t] = s * (1.0f / KP2);
}

// ---------------- classifier head (per graph) -----------------------------
__global__ __launch_bounds__(256) void head_k(const float* __restrict__ mg,
                                              const float* __restrict__ tw1,
                                              const float* __restrict__ tb1,
                                              const float* __restrict__ tw2,
                                              const float* __restrict__ tb2,
                                              const float* __restrict__ c1w,
                                              const float* __restrict__ c1b,
                                              const float* __restrict__ c2w,
                                              const float* __restrict__ c2b,
                                              float* __restrict__ out) {
    __shared__ float v0[CC], v1[CC], v2[64];
    const int g = blockIdx.x;
    const int t = threadIdx.x;
    v0[t] = mg[g * CC + t];
    __syncthreads();
    float s = tb1[t];
    for (int j = 0; j < CC; ++j) s = fmaf(v0[j], tw1[j * CC + t], s);
    v1[t] = s;
    __syncthreads();
    s = tb2[t];
    for (int j = 0; j < CC; ++j) s = fmaf(v1[j], tw2[j * CC + t], s);
    v0[t] = s;
    __syncthreads();
    if (t < 64) {
        float u = c1b[t];
        for (int j = 0; j < CC; ++j) u = fmaf(v0[j], c1w[j * 64 + t], u);
        v2[t] = fmaxf(u, 0.0f);
    }
    __syncthreads();
    if (t < 2) {
        float o = c2b[t];
        for (int j = 0; j < 64; ++j) o = fmaf(v2[j], c2w[j * 2 + t], o);
        v1[t] = o;
    }
    __syncthreads();
    if (t == 0) {
        float a = v1[0], b = v1[1];
        float mx = fmaxf(a, b);
        float lse = mx + logf(expf(a - mx) + expf(b - mx));
        out[g * 2 + 0] = a - lse;
        out[g * 2 + 1] = b - lse;
    }
}

// ---------------- launcher ----------------
extern "C" void kernel_launch(void* const* d_in, const int* in_sizes, int n_in,
                              void* d_out, int out_size, void* d_ws, size_t ws_size,
                              hipStream_t stream) {
    const float* x      = (const float*)d_in[0];
    const int*   ei     = (const int*)d_in[1];
    const int*   src    = ei;
    const int*   dst    = ei + EG;
    const float* W1     = (const float*)d_in[3];
    const float* a_src1 = (const float*)d_in[4];
    const float* a_dst1 = (const float*)d_in[5];
    const float* b1     = (const float*)d_in[6];
    const float* W2     = (const float*)d_in[7];
    const float* a_src2 = (const float*)d_in[8];
    const float* a_dst2 = (const float*)d_in[9];
    const float* b2     = (const float*)d_in[10];
    const float* p1_sw  = (const float*)d_in[11];
    const float* p1_sb  = (const float*)d_in[12];
    const float* p1_tw  = (const float*)d_in[13];
    const float* p1_tb  = (const float*)d_in[14];
    const float* p2_sw  = (const float*)d_in[15];
    const float* p2_sb  = (const float*)d_in[16];
    const float* p2_tw  = (const float*)d_in[17];
    const float* p2_tb  = (const float*)d_in[18];
    const float* c1w    = (const float*)d_in[19];
    const float* c1b    = (const float*)d_in[20];
    const float* c2w    = (const float*)d_in[21];
    const float* c2b    = (const float*)d_in[22];
    float* out = (float*)d_out;

    // workspace layout (floats)
    float* ws     = (float*)d_ws;
    float* z      = ws;                        // N*C
    float* feat   = z + (size_t)NN * CC;       // N*C
    float* es     = feat + (size_t)NN * CC;    // N*H
    float* ed     = es + NN * HH;              // N*H
    float* exself = ed + NN * HH;              // N*H
    float* ex     = exself + NN * HH;          // E*H
    int*   cnt    = (int*)(ex + (size_t)EG * HH);  // N
    int*   rowp   = cnt + NN;                  // N+1
    int*   cur    = rowp + NN + 1;             // N
    int*   esrc   = cur + NN;                  // E
    float* sc1    = (float*)(esrc + EG);       // N
    float* sc2    = sc1 + NN;                  // N
    int*   sel1   = (int*)(sc2 + NN);          // N
    int*   sel2   = sel1 + NN;                 // N
    float* w12    = (float*)(sel2 + NN);       // C
    float* b12    = w12 + CC;                  // 1 (padded to 64)
    float* mg     = b12 + 64;                  // B*C

    // ---- CSR build (dst-grouped), once; fuse_w12 early (inputs only) ----
    init_cnt<<<(NN + 255) / 256, 256, 0, stream>>>(cnt);
    csr_hist<<<(EG + 255) / 256, 256, 0, stream>>>(dst, cnt);
    csr_scan<<<1, 1024, 0, stream>>>(cnt, rowp, cur);
    csr_scatter<<<(EG + 255) / 256, 256, 0, stream>>>(src, dst, cur, esrc);
    fuse_w12<<<1, 256, 0, stream>>>(p1_tw, p2_sw, p1_tb, p2_sb, w12, b12);

    dim3 gemm_grid(NN / 128, CC / 64);

    // ---- GAT layer 1 ----
    gemm_fp32_attn<<<gemm_grid, 256, 0, stream>>>(x, W1, z, NN, FIN, CC,
                                                  a_src1, a_dst1, es, ed);
    softmax_csr<<<NN, 64, 0, stream>>>(rowp, esrc, es, ed, ex, exself);
    aggregate<<<NN, 256, 0, stream>>>(z, rowp, esrc, ex, exself, b1, feat,
                                      nullptr, nullptr, nullptr, nullptr,
                                      nullptr, nullptr);

    // ---- GAT layer 2 (scores fused into aggregate epilogue) ----
    gemm_fp32_attn<<<gemm_grid, 256, 0, stream>>>(feat, W2, z, NN, CC, CC,
                                                  a_src2, a_dst2, es, ed);
    softmax_csr<<<NN, 64, 0, stream>>>(rowp, esrc, es, ed, ex, exself);
    aggregate<<<NN, 256, 0, stream>>>(z, rowp, esrc, ex, exself, b2, feat,
                                      p1_sw, p1_sb, w12, b12, sc1, sc2);

    // ---- pooling + head ----
    topk_select<<<BG, NPG, 0, stream>>>(sc1, nullptr, sel1, KP1);
    topk_select<<<BG, NPG, 0, stream>>>(sc2, sel1, sel2, KP2);
    graph_mean<<<BG, 256, 0, stream>>>(feat, sel2, mg);
    head_k<<<BG, 256, 0, stream>>>(mg, p1_tw, p1_tb, p2_tw, p2_tb,
                                   c1w, c1b, c2w, c2b, out);
}

// Round 4
// 413.693 us; speedup vs baseline: 2.3242x; 1.2049x over previous
//
#include <hip/hip_runtime.h>
#include <math.h>

// ---------------- problem constants ----------------
constexpr int NN  = 32768;   // nodes
constexpr int BG  = 64;      // graphs
constexpr int NPG = 512;     // nodes per graph
constexpr int EG  = 524288;  // edges
constexpr int HH  = 4;       // heads
constexpr int FH  = 64;      // per-head dim
constexpr int CC  = 256;     // H*Fh
constexpr int FIN = 128;
constexpr int KP1 = 256;     // pool1 k
constexpr int KP2 = 128;     // pool2 k
constexpr int NS  = 4;       // register edge slots: fast path deg <= 64

__device__ inline float leaky02(float v) { return v > 0.0f ? v : 0.2f * v; }

// ---------------- GEMM: C[M,256] = A[M,K] @ B[K,256], fp32 ----------------
// BM=128, BN=64, BK=16, 256 threads, 8x4 per-thread tile.
// Row-blocks XCD-swizzled: graph g -> XCD g&7 (matches gat_edge consumer).
// Epilogue: es/ed = per-head dot(h, a_src/a_dst); head = blockIdx.y.
__global__ __launch_bounds__(256) void gemm_fp32_attn(const float* __restrict__ A,
                                                      const float* __restrict__ B,
                                                      float* __restrict__ Cm,
                                                      int K,
                                                      const float* __restrict__ a_src,
                                                      const float* __restrict__ a_dst,
                                                      float* __restrict__ es,
                                                      float* __restrict__ ed) {
    __shared__ float As[16][128];
    __shared__ float Bs[16][64];
    const int t  = threadIdx.x;
    // swizzle: bx -> (graph on XCD bx&7, 128-row chunk)
    const int bx = blockIdx.x;                 // 0..255
    const int c  = bx & 7;
    const int s  = bx >> 3;                    // 0..31
    const int g  = c + ((s >> 2) << 3);        // graph
    const int bm = g * NPG + ((s & 3) << 7);   // row base
    const int bn = blockIdx.y * 64;
    const int tx = t & 15;
    const int ty = t >> 4;
    const int ar = t >> 2;
    const int ac = (t & 3) << 2;
    const int br = t >> 4;
    const int bc = (t & 15) << 2;
    const int Nc = CC;

    float acc[8][4];
#pragma unroll
    for (int i = 0; i < 8; ++i)
#pragma unroll
        for (int j = 0; j < 4; ++j) acc[i][j] = 0.0f;

    for (int k0 = 0; k0 < K; k0 += 16) {
        float4 a0 = *(const float4*)(A + (size_t)(bm + ar) * K + k0 + ac);
        float4 a1 = *(const float4*)(A + (size_t)(bm + ar + 64) * K + k0 + ac);
        float4 b0 = *(const float4*)(B + (size_t)(k0 + br) * Nc + bn + bc);
        __syncthreads();
        As[ac + 0][ar] = a0.x; As[ac + 1][ar] = a0.y;
        As[ac + 2][ar] = a0.z; As[ac + 3][ar] = a0.w;
        As[ac + 0][ar + 64] = a1.x; As[ac + 1][ar + 64] = a1.y;
        As[ac + 2][ar + 64] = a1.z; As[ac + 3][ar + 64] = a1.w;
        *(float4*)&Bs[br][bc] = b0;
        __syncthreads();
#pragma unroll
        for (int k = 0; k < 16; ++k) {
            float av[8], bv[4];
            *(float4*)(av)     = *(const float4*)&As[k][ty * 8];
            *(float4*)(av + 4) = *(const float4*)&As[k][ty * 8 + 4];
            *(float4*)(bv)     = *(const float4*)&Bs[k][tx * 4];
#pragma unroll
            for (int i = 0; i < 8; ++i)
#pragma unroll
                for (int j = 0; j < 4; ++j)
                    acc[i][j] = fmaf(av[i], bv[j], acc[i][j]);
        }
    }
#pragma unroll
    for (int i = 0; i < 8; ++i) {
        float4 v = make_float4(acc[i][0], acc[i][1], acc[i][2], acc[i][3]);
        *(float4*)(Cm + (size_t)(bm + ty * 8 + i) * Nc + bn + tx * 4) = v;
    }

    // attention-coefficient epilogue (accumulators hold h rows)
    {
        const float4 as = *(const float4*)(a_src + bn + tx * 4);
        const float4 ad = *(const float4*)(a_dst + bn + tx * 4);
        const int head = blockIdx.y;
#pragma unroll
        for (int i = 0; i < 8; ++i) {
            float ps = acc[i][0] * as.x + acc[i][1] * as.y +
                       acc[i][2] * as.z + acc[i][3] * as.w;
            float pd = acc[i][0] * ad.x + acc[i][1] * ad.y +
                       acc[i][2] * ad.z + acc[i][3] * ad.w;
#pragma unroll
            for (int o = 8; o >= 1; o >>= 1) {
                ps += __shfl_down(ps, o, 16);
                pd += __shfl_down(pd, o, 16);
            }
            if (tx == 0) {
                es[(bm + ty * 8 + i) * HH + head] = ps;
                ed[(bm + ty * 8 + i) * HH + head] = pd;
            }
        }
    }
}

// ---------------- prep: zero cnt + fused pool2 score weights --------------
__global__ __launch_bounds__(256) void prep(int* __restrict__ cnt,
                                            const float* __restrict__ tw1,
                                            const float* __restrict__ sw2,
                                            const float* __restrict__ tb1,
                                            const float* __restrict__ sb2,
                                            float* __restrict__ w12,
                                            float* __restrict__ b12) {
    if (blockIdx.x < 128) {
        cnt[blockIdx.x * 256 + threadIdx.x] = 0;
    } else {
        int j = threadIdx.x;
        float s = 0.0f;
        for (int o = 0; o < CC; ++o) s += tw1[j * CC + o] * sw2[o];
        w12[j] = s;
        if (j == 0) {
            float b = 0.0f;
            for (int o = 0; o < CC; ++o) b += tb1[o] * sw2[o];
            *b12 = b + sb2[0];
        }
    }
}

// ---------------- CSR build (by dst) ----------------
__global__ void csr_hist(const int* __restrict__ dst, int* cnt) {
    int e = blockIdx.x * 256 + threadIdx.x;
    if (e < EG) atomicAdd(&cnt[dst[e]], 1);
}
__global__ __launch_bounds__(1024) void csr_scan(const int* __restrict__ cnt,
                                                 int* __restrict__ rowp,
                                                 int* __restrict__ cur) {
    __shared__ int tmp[1024];
    const int t = threadIdx.x;
    const int base = t * 32;
    int local[32];
    int s = 0;
#pragma unroll
    for (int i = 0; i < 32; ++i) { local[i] = s; s += cnt[base + i]; }
    tmp[t] = s;
    __syncthreads();
    for (int o = 1; o < 1024; o <<= 1) {
        int v = (t >= o) ? tmp[t - o] : 0;
        __syncthreads();
        tmp[t] += v;
        __syncthreads();
    }
    int off = tmp[t] - s;  // exclusive prefix
#pragma unroll
    for (int i = 0; i < 32; ++i) {
        int p = off + local[i];
        rowp[base + i] = p;
        cur[base + i] = p;
    }
    if (t == 1023) rowp[NN] = off + s;
}
__global__ void csr_scatter(const int* __restrict__ src, const int* __restrict__ dst,
                            int* cur, int* __restrict__ esrc) {
    int e = blockIdx.x * 256 + threadIdx.x;
    if (e < EG) {
        int p = atomicAdd(&cur[dst[e]], 1);
        esrc[p] = src[e];
    }
}

// ---------------- fused GAT edge stage: softmax + aggregate + ELU ----------
// One wave per dst node, 4 waves/block, no barriers, XCD-swizzled.
// Phase A (lane = (edge_slot ei = l>>2, head h = l&3)): alpha in registers.
// Phase B (lane = channels 4l..4l+3, head h2 = l>>4): float4 gather-FMA,
// alpha/src broadcast via shfl. Optional score epilogue (layer 2).
__global__ __launch_bounds__(256) void gat_edge(const float* __restrict__ z,
                                                const int* __restrict__ rowp,
                                                const int* __restrict__ esrc,
                                                const float* __restrict__ es,
                                                const float* __restrict__ ed,
                                                const float* __restrict__ bias,
                                                float* __restrict__ out,
                                                const float* __restrict__ sw1,
                                                const float* __restrict__ sb1,
                                                const float* __restrict__ w12,
                                                const float* __restrict__ b12,
                                                float* __restrict__ sc1,
                                                float* __restrict__ sc2) {
    const int w = threadIdx.x >> 6;
    const int l = threadIdx.x & 63;
    // block -> 4 consecutive nodes of one graph; graph gph -> XCD gph&7
    const int b    = blockIdx.x;              // 0..8191
    const int xcd  = b & 7;
    const int slot = b >> 3;                  // 0..1023
    const int gph  = xcd + ((slot >> 7) << 3);
    const int d    = gph * NPG + ((slot & 127) << 2) + w;

    const int h  = l & 3;
    const int ei = l >> 2;
    const int h2 = l >> 4;
    const int beg = rowp[d];
    const int deg = rowp[d + 1] - beg;

    const float4 zv = *(const float4*)(z + (size_t)d * CC + 4 * l);
    float4 acc;

    if (deg <= 16 * NS) {
        // ---- phase A: register softmax ----
        const float edh = ed[d * HH + h];
        int   sidx[NS];
        float v[NS];
        float vmax = -INFINITY, eself = 0.0f;
        float vself = 0.0f;
        if (ei == 0) {
            vself = leaky02(es[d * HH + h] + edh);
            vmax = vself;
        }
#pragma unroll
        for (int j = 0; j < NS; ++j) {
            int i = ei + 16 * j;
            if (i < deg) {
                sidx[j] = esrc[beg + i];
                v[j] = leaky02(es[sidx[j] * HH + h] + edh);
                vmax = fmaxf(vmax, v[j]);
            }
        }
#pragma unroll
        for (int o = 4; o <= 32; o <<= 1) vmax = fmaxf(vmax, __shfl_xor(vmax, o));
        float dsum = 0.0f;
#pragma unroll
        for (int j = 0; j < NS; ++j) {
            int i = ei + 16 * j;
            if (i < deg) { v[j] = __expf(v[j] - vmax); dsum += v[j]; }
        }
        if (ei == 0) { eself = __expf(vself - vmax); dsum += eself; }
#pragma unroll
        for (int o = 4; o <= 32; o <<= 1) dsum += __shfl_xor(dsum, o);
        const float inv = 1.0f / (dsum + 1e-16f);
#pragma unroll
        for (int j = 0; j < NS; ++j) v[j] *= inv;   // normalized alpha
        eself *= inv;

        // ---- phase B: float4 aggregation ----
        float aself = __shfl(eself, h2);  // lanes 0..3 hold per-head self alpha
        acc = make_float4(aself * zv.x, aself * zv.y, aself * zv.z, aself * zv.w);
#pragma unroll
        for (int j = 0; j < NS; ++j) {
            if (16 * j < deg) {
                for (int s = 0; s < 16; ++s) {
                    int i = 16 * j + s;
                    if (i >= deg) break;
                    int   srcn = __shfl(sidx[j], s * 4);
                    float a    = __shfl(v[j],    s * 4 + h2);
                    float4 zs  = *(const float4*)(z + (size_t)srcn * CC + 4 * l);
                    acc.x = fmaf(a, zs.x, acc.x);
                    acc.y = fmaf(a, zs.y, acc.y);
                    acc.z = fmaf(a, zs.z, acc.z);
                    acc.w = fmaf(a, zs.w, acc.w);
                }
            }
        }
    } else {
        // ---- generic slow path (never taken for the fixed input) ----
        const float edh = ed[d * HH + h];
        float vmax = (ei == 0) ? leaky02(es[d * HH + h] + edh) : -INFINITY;
        for (int i = ei; i < deg; i += 16)
            vmax = fmaxf(vmax, leaky02(es[esrc[beg + i] * HH + h] + edh));
#pragma unroll
        for (int o = 4; o <= 32; o <<= 1) vmax = fmaxf(vmax, __shfl_xor(vmax, o));
        float dsum = (ei == 0) ? __expf(leaky02(es[d * HH + h] + edh) - vmax) : 0.0f;
        for (int i = ei; i < deg; i += 16)
            dsum += __expf(leaky02(es[esrc[beg + i] * HH + h] + edh) - vmax);
#pragma unroll
        for (int o = 4; o <= 32; o <<= 1) dsum += __shfl_xor(dsum, o);
        const float inv = 1.0f / (dsum + 1e-16f);

        const float vmaxc = __shfl(vmax, h2);  // lane h2 has head h2
        const float invc  = __shfl(inv,  h2);
        const float edh4  = ed[d * HH + h2];
        float a0 = __expf(leaky02(es[d * HH + h2] + edh4) - vmaxc) * invc;
        acc = make_float4(a0 * zv.x, a0 * zv.y, a0 * zv.z, a0 * zv.w);
        for (int i = 0; i < deg; ++i) {
            int srcn = esrc[beg + i];
            float a = __expf(leaky02(es[srcn * HH + h2] + edh4) - vmaxc) * invc;
            float4 zs = *(const float4*)(z + (size_t)srcn * CC + 4 * l);
            acc.x = fmaf(a, zs.x, acc.x);
            acc.y = fmaf(a, zs.y, acc.y);
            acc.z = fmaf(a, zs.z, acc.z);
            acc.w = fmaf(a, zs.w, acc.w);
        }
    }

    // ---- epilogue: bias + ELU (+ optional pooling scores) ----
    const float4 bv = *(const float4*)(bias + 4 * l);
    float4 o;
    o.x = acc.x + bv.x; o.x = o.x > 0.0f ? o.x : expm1f(o.x);
    o.y = acc.y + bv.y; o.y = o.y > 0.0f ? o.y : expm1f(o.y);
    o.z = acc.z + bv.z; o.z = o.z > 0.0f ? o.z : expm1f(o.z);
    o.w = acc.w + bv.w; o.w = o.w > 0.0f ? o.w : expm1f(o.w);
    *(float4*)(out + (size_t)d * CC + 4 * l) = o;

    if (sc1) {
        const float4 s1 = *(const float4*)(sw1 + 4 * l);
        const float4 s2 = *(const float4*)(w12 + 4 * l);
        float r1 = o.x * s1.x + o.y * s1.y + o.z * s1.z + o.w * s1.w;
        float r2 = o.x * s2.x + o.y * s2.y + o.z * s2.z + o.w * s2.w;
#pragma unroll
        for (int off = 32; off >= 1; off >>= 1) {
            r1 += __shfl_xor(r1, off);
            r2 += __shfl_xor(r2, off);
        }
        if (l == 0) {
            sc1[d] = r1 + sb1[0];
            sc2[d] = r2 + b12[0];
        }
    }
}

// ---------------- fused pooling + classifier head (one block per graph) ---
__global__ __launch_bounds__(512) void pool_head(const float* __restrict__ feat,
                                                 const float* __restrict__ sc1,
                                                 const float* __restrict__ sc2,
                                                 const float* __restrict__ tw1,
                                                 const float* __restrict__ tb1,
                                                 const float* __restrict__ tw2,
                                                 const float* __restrict__ tb2,
                                                 const float* __restrict__ c1w,
                                                 const float* __restrict__ c1b,
                                                 const float* __restrict__ c2w,
                                                 const float* __restrict__ c2b,
                                                 float* __restrict__ out) {
    __shared__ float s[NPG];
    __shared__ unsigned char keep[NPG];
    __shared__ float v0[CC], v1[CC], v2[64];
    const int g = blockIdx.x;
    const int i = threadIdx.x;
    const int t = i & 255;
    const int half = i >> 8;

    // ---- top-k1 over sc1 (rank counting; lower index wins ties) ----
    float my = sc1[g * NPG + i];
    s[i] = my;
    __syncthreads();
    int rank = 0;
    for (int j = 0; j < NPG; ++j) {
        float sj = s[j];
        rank += (sj > my) || (sj == my && j < i);
    }
    int k1 = rank < KP1;
    __syncthreads();
    // ---- top-k2 over sc2 restricted to k1 set ----
    float my2 = k1 ? sc2[g * NPG + i] : -INFINITY;
    s[i] = my2;
    __syncthreads();
    rank = 0;
    for (int j = 0; j < NPG; ++j) {
        float sj = s[j];
        rank += (sj > my2) || (sj == my2 && j < i);
    }
    keep[i] = (unsigned char)(k1 && rank < KP2);
    __syncthreads();

    // ---- mean over selected rows (split across two thread-halves) ----
    float sum = 0.0f;
    for (int j = half * 256; j < half * 256 + 256; ++j)
        if (keep[j]) sum += feat[(size_t)(g * NPG + j) * CC + t];
    if (half == 0) v0[t] = sum;
    __syncthreads();
    if (half == 1) v0[t] += sum;
    __syncthreads();
    if (i < CC) v0[i] *= (1.0f / KP2);
    __syncthreads();

    // ---- head: (v0@tw1+tb1)@tw2+tb2 -> relu(@c1w+c1b) -> @c2w+c2b -> lsm ---
    if (i < CC) {
        float a = tb1[i];
        for (int j = 0; j < CC; ++j) a = fmaf(v0[j], tw1[j * CC + i], a);
        v1[i] = a;
    }
    __syncthreads();
    if (i < CC) {
        float a = tb2[i];
        for (int j = 0; j < CC; ++j) a = fmaf(v1[j], tw2[j * CC + i], a);
        s[i] = a;
    }
    __syncthreads();
    if (i < 64) {
        float u = c1b[i];
        for (int j = 0; j < CC; ++j) u = fmaf(s[j], c1w[j * 64 + i], u);
        v2[i] = fmaxf(u, 0.0f);
    }
    __syncthreads();
    if (i < 2) {
        float o = c2b[i];
        for (int j = 0; j < 64; ++j) o = fmaf(v2[j], c2w[j * 2 + i], o);
        s[i] = o;
    }
    __syncthreads();
    if (i == 0) {
        float a = s[0], bq = s[1];
        float mx = fmaxf(a, bq);
        float lse = mx + logf(expf(a - mx) + expf(bq - mx));
        out[g * 2 + 0] = a - lse;
        out[g * 2 + 1] = bq - lse;
    }
}

// ---------------- launcher ----------------
extern "C" void kernel_launch(void* const* d_in, const int* in_sizes, int n_in,
                              void* d_out, int out_size, void* d_ws, size_t ws_size,
                              hipStream_t stream) {
    const float* x      = (const float*)d_in[0];
    const int*   ei     = (const int*)d_in[1];
    const int*   src    = ei;
    const int*   dst    = ei + EG;
    const float* W1     = (const float*)d_in[3];
    const float* a_src1 = (const float*)d_in[4];
    const float* a_dst1 = (const float*)d_in[5];
    const float* b1     = (const float*)d_in[6];
    const float* W2     = (const float*)d_in[7];
    const float* a_src2 = (const float*)d_in[8];
    const float* a_dst2 = (const float*)d_in[9];
    const float* b2     = (const float*)d_in[10];
    const float* p1_sw  = (const float*)d_in[11];
    const float* p1_sb  = (const float*)d_in[12];
    const float* p1_tw  = (const float*)d_in[13];
    const float* p1_tb  = (const float*)d_in[14];
    const float* p2_sw  = (const float*)d_in[15];
    const float* p2_sb  = (const float*)d_in[16];
    const float* p2_tw  = (const float*)d_in[17];
    const float* p2_tb  = (const float*)d_in[18];
    const float* c1w    = (const float*)d_in[19];
    const float* c1b    = (const float*)d_in[20];
    const float* c2w    = (const float*)d_in[21];
    const float* c2b    = (const float*)d_in[22];
    float* out = (float*)d_out;

    // workspace layout (floats)
    float* ws   = (float*)d_ws;
    float* z    = ws;                          // N*C
    float* feat = z + (size_t)NN * CC;         // N*C
    float* es   = feat + (size_t)NN * CC;      // N*H
    float* ed   = es + NN * HH;                // N*H
    int*   cnt  = (int*)(ed + NN * HH);        // N
    int*   rowp = cnt + NN;                    // N+1
    int*   cur  = rowp + NN + 1;               // N
    int*   esrc = cur + NN;                    // E
    float* sc1  = (float*)(esrc + EG);         // N
    float* sc2  = sc1 + NN;                    // N
    float* w12  = sc2 + NN;                    // C
    float* b12  = w12 + CC;                    // 1 (padded to 64)

    // ---- prep (zero cnt + w12) and CSR build (dst-grouped) ----
    prep<<<129, 256, 0, stream>>>(cnt, p1_tw, p2_sw, p1_tb, p2_sb, w12, b12);
    csr_hist<<<(EG + 255) / 256, 256, 0, stream>>>(dst, cnt);
    csr_scan<<<1, 1024, 0, stream>>>(cnt, rowp, cur);
    csr_scatter<<<(EG + 255) / 256, 256, 0, stream>>>(src, dst, cur, esrc);

    dim3 gemm_grid(NN / 128, CC / 64);

    // ---- GAT layer 1 ----
    gemm_fp32_attn<<<gemm_grid, 256, 0, stream>>>(x, W1, z, FIN,
                                                  a_src1, a_dst1, es, ed);
    gat_edge<<<NN / 4, 256, 0, stream>>>(z, rowp, esrc, es, ed, b1, feat,
                                         nullptr, nullptr, nullptr, nullptr,
                                         nullptr, nullptr);

    // ---- GAT layer 2 (pooling scores fused into epilogue) ----
    gemm_fp32_attn<<<gemm_grid, 256, 0, stream>>>(feat, W2, z, CC,
                                                  a_src2, a_dst2, es, ed);
    gat_edge<<<NN / 4, 256, 0, stream>>>(z, rowp, esrc, es, ed, b2, feat,
                                         p1_sw, p1_sb, w12, b12, sc1, sc2);

    // ---- fused pooling + head ----
    pool_head<<<BG, 512, 0, stream>>>(feat, sc1, sc2, p1_tw, p1_tb,
                                      p2_tw, p2_tb, c1w, c1b, c2w, c2b, out);
}

// Round 6
// 393.370 us; speedup vs baseline: 2.4443x; 1.0517x over previous
//
#include <hip/hip_runtime.h>
#include <math.h>

// ---------------- problem constants ----------------
constexpr int NN  = 32768;   // nodes
constexpr int BG  = 64;      // graphs
constexpr int NPG = 512;     // nodes per graph
constexpr int EG  = 524288;  // edges
constexpr int HH  = 4;       // heads
constexpr int FH  = 64;      // per-head dim
constexpr int CC  = 256;     // H*Fh
constexpr int FIN = 128;
constexpr int KP1 = 256;     // pool1 k
constexpr int KP2 = 128;     // pool2 k
constexpr int NS  = 4;       // register edge slots: fast path deg <= 64

__device__ inline float leaky02(float v) { return v > 0.0f ? v : 0.2f * v; }

// ---------------- GEMM: C[M,256] = A[M,K] @ B[K,256], fp32 ----------------
// BM=128, BN=64, BK=16, 256 threads, 8x4 per-thread tile.
// Row-blocks XCD-swizzled: graph g -> XCD g&7 (matches gat_edge consumer).
// Epilogue: es/ed = per-head dot(h, a_src/a_dst); head = blockIdx.y.
__global__ __launch_bounds__(256) void gemm_fp32_attn(const float* __restrict__ A,
                                                      const float* __restrict__ B,
                                                      float* __restrict__ Cm,
                                                      int K,
                                                      const float* __restrict__ a_src,
                                                      const float* __restrict__ a_dst,
                                                      float* __restrict__ es,
                                                      float* __restrict__ ed) {
    __shared__ float As[16][128];
    __shared__ float Bs[16][64];
    const int t  = threadIdx.x;
    // swizzle: bx -> (graph on XCD bx&7, 128-row chunk)
    const int bx = blockIdx.x;                 // 0..255
    const int c  = bx & 7;
    const int s  = bx >> 3;                    // 0..31
    const int g  = c + ((s >> 2) << 3);        // graph
    const int bm = g * NPG + ((s & 3) << 7);   // row base
    const int bn = blockIdx.y * 64;
    const int tx = t & 15;
    const int ty = t >> 4;
    const int ar = t >> 2;
    const int ac = (t & 3) << 2;
    const int br = t >> 4;
    const int bc = (t & 15) << 2;
    const int Nc = CC;

    float acc[8][4];
#pragma unroll
    for (int i = 0; i < 8; ++i)
#pragma unroll
        for (int j = 0; j < 4; ++j) acc[i][j] = 0.0f;

    for (int k0 = 0; k0 < K; k0 += 16) {
        float4 a0 = *(const float4*)(A + (size_t)(bm + ar) * K + k0 + ac);
        float4 a1 = *(const float4*)(A + (size_t)(bm + ar + 64) * K + k0 + ac);
        float4 b0 = *(const float4*)(B + (size_t)(k0 + br) * Nc + bn + bc);
        __syncthreads();
        As[ac + 0][ar] = a0.x; As[ac + 1][ar] = a0.y;
        As[ac + 2][ar] = a0.z; As[ac + 3][ar] = a0.w;
        As[ac + 0][ar + 64] = a1.x; As[ac + 1][ar + 64] = a1.y;
        As[ac + 2][ar + 64] = a1.z; As[ac + 3][ar + 64] = a1.w;
        *(float4*)&Bs[br][bc] = b0;
        __syncthreads();
#pragma unroll
        for (int k = 0; k < 16; ++k) {
            float av[8], bv[4];
            *(float4*)(av)     = *(const float4*)&As[k][ty * 8];
            *(float4*)(av + 4) = *(const float4*)&As[k][ty * 8 + 4];
            *(float4*)(bv)     = *(const float4*)&Bs[k][tx * 4];
#pragma unroll
            for (int i = 0; i < 8; ++i)
#pragma unroll
                for (int j = 0; j < 4; ++j)
                    acc[i][j] = fmaf(av[i], bv[j], acc[i][j]);
        }
    }
#pragma unroll
    for (int i = 0; i < 8; ++i) {
        float4 v = make_float4(acc[i][0], acc[i][1], acc[i][2], acc[i][3]);
        *(float4*)(Cm + (size_t)(bm + ty * 8 + i) * Nc + bn + tx * 4) = v;
    }

    // attention-coefficient epilogue (accumulators hold h rows)
    {
        const float4 as = *(const float4*)(a_src + bn + tx * 4);
        const float4 ad = *(const float4*)(a_dst + bn + tx * 4);
        const int head = blockIdx.y;
#pragma unroll
        for (int i = 0; i < 8; ++i) {
            float ps = acc[i][0] * as.x + acc[i][1] * as.y +
                       acc[i][2] * as.z + acc[i][3] * as.w;
            float pd = acc[i][0] * ad.x + acc[i][1] * ad.y +
                       acc[i][2] * ad.z + acc[i][3] * ad.w;
#pragma unroll
            for (int o = 8; o >= 1; o >>= 1) {
                ps += __shfl_down(ps, o, 16);
                pd += __shfl_down(pd, o, 16);
            }
            if (tx == 0) {
                es[(bm + ty * 8 + i) * HH + head] = ps;
                ed[(bm + ty * 8 + i) * HH + head] = pd;
            }
        }
    }
}

// ---------------- prep: zero cnt + w12 + T = tw2@c1w + bc2 = tb2@c1w -------
// blocks 0..127: zero cnt. block 128: w12/b12. blocks 129..192: T rows
// (4 rows x 64 cols per 256-thread block). block 193: bc2.
__global__ __launch_bounds__(256) void prep(int* __restrict__ cnt,
                                            const float* __restrict__ tw1,
                                            const float* __restrict__ sw2,
                                            const float* __restrict__ tb1,
                                            const float* __restrict__ sb2,
                                            float* __restrict__ w12,
                                            float* __restrict__ b12,
                                            const float* __restrict__ tw2,
                                            const float* __restrict__ c1w,
                                            const float* __restrict__ tb2,
                                            float* __restrict__ T,
                                            float* __restrict__ bc2) {
    const int b = blockIdx.x;
    const int t = threadIdx.x;
    if (b < 128) {
        cnt[b * 256 + t] = 0;
    } else if (b == 128) {
        float s = 0.0f;
        for (int o = 0; o < CC; ++o) s += tw1[t * CC + o] * sw2[o];
        w12[t] = s;
        if (t == 0) {
            float bb = 0.0f;
            for (int o = 0; o < CC; ++o) bb += tb1[o] * sw2[o];
            *b12 = bb + sb2[0];
        }
    } else if (b < 193) {
        const int r = (b - 129) * 4 + (t >> 6);   // 4 rows per block
        const int cth = t & 63;
        float s = 0.0f;
        for (int j = 0; j < CC; ++j) s = fmaf(tw2[r * CC + j], c1w[j * 64 + cth], s);
        T[r * 64 + cth] = s;
    } else if (t < 64) {
        float s = 0.0f;
        for (int j = 0; j < CC; ++j) s = fmaf(tb2[j], c1w[j * 64 + t], s);
        bc2[t] = s;
    }
}

// ---------------- fold_W: Wc = tw1@T, bc = tb1@T + bc2 + c1b --------------
// blocks 0..63: Wc rows (4 rows x 64 cols per block). block 64: bc.
__global__ __launch_bounds__(256) void fold_W(const float* __restrict__ tw1,
                                              const float* __restrict__ T,
                                              const float* __restrict__ tb1,
                                              const float* __restrict__ bc2,
                                              const float* __restrict__ c1b,
                                              float* __restrict__ Wc,
                                              float* __restrict__ bc) {
    const int b = blockIdx.x;
    const int t = threadIdx.x;
    if (b < 64) {
        const int r = b * 4 + (t >> 6);           // 4 rows per block
        const int cth = t & 63;
        float s = 0.0f;
        for (int j = 0; j < CC; ++j) s = fmaf(tw1[r * CC + j], T[j * 64 + cth], s);
        Wc[r * 64 + cth] = s;
    } else if (t < 64) {
        float s = 0.0f;
        for (int j = 0; j < CC; ++j) s = fmaf(tb1[j], T[j * 64 + t], s);
        bc[t] = s + bc2[t] + c1b[t];
    }
}

// ---------------- CSR build (by dst) ----------------
__global__ void csr_hist(const int* __restrict__ dst, int* cnt) {
    int e = blockIdx.x * 256 + threadIdx.x;
    if (e < EG) atomicAdd(&cnt[dst[e]], 1);
}
__global__ __launch_bounds__(1024) void csr_scan(const int* __restrict__ cnt,
                                                 int* __restrict__ rowp,
                                                 int* __restrict__ cur) {
    __shared__ int tmp[1024];
    const int t = threadIdx.x;
    const int base = t * 32;
    int local[32];
    int s = 0;
#pragma unroll
    for (int i = 0; i < 32; ++i) { local[i] = s; s += cnt[base + i]; }
    tmp[t] = s;
    __syncthreads();
    for (int o = 1; o < 1024; o <<= 1) {
        int v = (t >= o) ? tmp[t - o] : 0;
        __syncthreads();
        tmp[t] += v;
        __syncthreads();
    }
    int off = tmp[t] - s;  // exclusive prefix
#pragma unroll
    for (int i = 0; i < 32; ++i) {
        int p = off + local[i];
        rowp[base + i] = p;
        cur[base + i] = p;
    }
    if (t == 1023) rowp[NN] = off + s;
}
__global__ void csr_scatter(const int* __restrict__ src, const int* __restrict__ dst,
                            int* cur, int* __restrict__ esrc) {
    int e = blockIdx.x * 256 + threadIdx.x;
    if (e < EG) {
        int p = atomicAdd(&cur[dst[e]], 1);
        esrc[p] = src[e];
    }
}

// ---------------- fused GAT edge stage: softmax + aggregate + ELU ----------
// One wave per dst node, 4 waves/block, no barriers, XCD-swizzled.
__global__ __launch_bounds__(256) void gat_edge(const float* __restrict__ z,
                                                const int* __restrict__ rowp,
                                                const int* __restrict__ esrc,
                                                const float* __restrict__ es,
                                                const float* __restrict__ ed,
                                                const float* __restrict__ bias,
                                                float* __restrict__ out,
                                                const float* __restrict__ sw1,
                                                const float* __restrict__ sb1,
                                                const float* __restrict__ w12,
                                                const float* __restrict__ b12,
                                                float* __restrict__ sc1,
                                                float* __restrict__ sc2) {
    const int w = threadIdx.x >> 6;
    const int l = threadIdx.x & 63;
    const int b    = blockIdx.x;              // 0..8191
    const int xcd  = b & 7;
    const int slot = b >> 3;                  // 0..1023
    const int gph  = xcd + ((slot >> 7) << 3);
    const int d    = gph * NPG + ((slot & 127) << 2) + w;

    const int h  = l & 3;
    const int ei = l >> 2;
    const int h2 = l >> 4;
    const int beg = rowp[d];
    const int deg = rowp[d + 1] - beg;

    const float4 zv = *(const float4*)(z + (size_t)d * CC + 4 * l);
    float4 acc;

    if (deg <= 16 * NS) {
        // ---- phase A: register softmax ----
        const float edh = ed[d * HH + h];
        int   sidx[NS];
        float v[NS];
        float vmax = -INFINITY, eself = 0.0f;
        float vself = 0.0f;
        if (ei == 0) {
            vself = leaky02(es[d * HH + h] + edh);
            vmax = vself;
        }
#pragma unroll
        for (int j = 0; j < NS; ++j) {
            int i = ei + 16 * j;
            if (i < deg) {
                sidx[j] = esrc[beg + i];
                v[j] = leaky02(es[sidx[j] * HH + h] + edh);
                vmax = fmaxf(vmax, v[j]);
            }
        }
#pragma unroll
        for (int o = 4; o <= 32; o <<= 1) vmax = fmaxf(vmax, __shfl_xor(vmax, o));
        float dsum = 0.0f;
#pragma unroll
        for (int j = 0; j < NS; ++j) {
            int i = ei + 16 * j;
            if (i < deg) { v[j] = __expf(v[j] - vmax); dsum += v[j]; }
        }
        if (ei == 0) { eself = __expf(vself - vmax); dsum += eself; }
#pragma unroll
        for (int o = 4; o <= 32; o <<= 1) dsum += __shfl_xor(dsum, o);
        const float inv = 1.0f / (dsum + 1e-16f);
#pragma unroll
        for (int j = 0; j < NS; ++j) v[j] *= inv;   // normalized alpha
        eself *= inv;

        // ---- phase B: float4 aggregation ----
        float aself = __shfl(eself, h2);
        acc = make_float4(aself * zv.x, aself * zv.y, aself * zv.z, aself * zv.w);
#pragma unroll
        for (int j = 0; j < NS; ++j) {
            if (16 * j < deg) {
                for (int s = 0; s < 16; ++s) {
                    int i = 16 * j + s;
                    if (i >= deg) break;
                    int   srcn = __shfl(sidx[j], s * 4);
                    float a    = __shfl(v[j],    s * 4 + h2);
                    float4 zs  = *(const float4*)(z + (size_t)srcn * CC + 4 * l);
                    acc.x = fmaf(a, zs.x, acc.x);
                    acc.y = fmaf(a, zs.y, acc.y);
                    acc.z = fmaf(a, zs.z, acc.z);
                    acc.w = fmaf(a, zs.w, acc.w);
                }
            }
        }
    } else {
        // ---- generic slow path (never taken for the fixed input) ----
        const float edh = ed[d * HH + h];
        float vmax = (ei == 0) ? leaky02(es[d * HH + h] + edh) : -INFINITY;
        for (int i = ei; i < deg; i += 16)
            vmax = fmaxf(vmax, leaky02(es[esrc[beg + i] * HH + h] + edh));
#pragma unroll
        for (int o = 4; o <= 32; o <<= 1) vmax = fmaxf(vmax, __shfl_xor(vmax, o));
        float dsum = (ei == 0) ? __expf(leaky02(es[d * HH + h] + edh) - vmax) : 0.0f;
        for (int i = ei; i < deg; i += 16)
            dsum += __expf(leaky02(es[esrc[beg + i] * HH + h] + edh) - vmax);
#pragma unroll
        for (int o = 4; o <= 32; o <<= 1) dsum += __shfl_xor(dsum, o);
        const float inv = 1.0f / (dsum + 1e-16f);

        const float vmaxc = __shfl(vmax, h2);
        const float invc  = __shfl(inv,  h2);
        const float edh4  = ed[d * HH + h2];
        float a0 = __expf(leaky02(es[d * HH + h2] + edh4) - vmaxc) * invc;
        acc = make_float4(a0 * zv.x, a0 * zv.y, a0 * zv.z, a0 * zv.w);
        for (int i = 0; i < deg; ++i) {
            int srcn = esrc[beg + i];
            float a = __expf(leaky02(es[srcn * HH + h2] + edh4) - vmaxc) * invc;
            float4 zs = *(const float4*)(z + (size_t)srcn * CC + 4 * l);
            acc.x = fmaf(a, zs.x, acc.x);
            acc.y = fmaf(a, zs.y, acc.y);
            acc.z = fmaf(a, zs.z, acc.z);
            acc.w = fmaf(a, zs.w, acc.w);
        }
    }

    // ---- epilogue: bias + ELU (+ optional pooling scores) ----
    const float4 bv = *(const float4*)(bias + 4 * l);
    float4 o;
    o.x = acc.x + bv.x; o.x = o.x > 0.0f ? o.x : expm1f(o.x);
    o.y = acc.y + bv.y; o.y = o.y > 0.0f ? o.y : expm1f(o.y);
    o.z = acc.z + bv.z; o.z = o.z > 0.0f ? o.z : expm1f(o.z);
    o.w = acc.w + bv.w; o.w = o.w > 0.0f ? o.w : expm1f(o.w);
    *(float4*)(out + (size_t)d * CC + 4 * l) = o;

    if (sc1) {
        const float4 s1 = *(const float4*)(sw1 + 4 * l);
        const float4 s2 = *(const float4*)(w12 + 4 * l);
        float r1 = o.x * s1.x + o.y * s1.y + o.z * s1.z + o.w * s1.w;
        float r2 = o.x * s2.x + o.y * s2.y + o.z * s2.z + o.w * s2.w;
#pragma unroll
        for (int off = 32; off >= 1; off >>= 1) {
            r1 += __shfl_xor(r1, off);
            r2 += __shfl_xor(r2, off);
        }
        if (l == 0) {
            sc1[d] = r1 + sb1[0];
            sc2[d] = r2 + b12[0];
        }
    }
}

// ---------------- fused pooling + folded head (one block per graph) -------
// topk1/topk2 -> masked float4 mean -> relu(mean@Wc+bc) -> @c2w+c2b -> lsm
__global__ __launch_bounds__(512) void pool_head(const float* __restrict__ feat,
                                                 const float* __restrict__ sc1,
                                                 const float* __restrict__ sc2,
                                                 const float* __restrict__ Wc,
                                                 const float* __restrict__ bc,
                                                 const float* __restrict__ c2w,
                                                 const float* __restrict__ c2b,
                                                 float* __restrict__ out) {
    __shared__ float s[NPG];
    __shared__ unsigned char keep[NPG];
    __shared__ float vbuf[8][CC];
    __shared__ float v0[CC];
    __shared__ float part[8][64];
    __shared__ float v2[64];
    const int g = blockIdx.x;
    const int i = threadIdx.x;

    // ---- top-k1 (rank counting; lower index wins ties) ----
    float my = sc1[g * NPG + i];
    s[i] = my;
    __syncthreads();
    int rank = 0;
    for (int j = 0; j < NPG; ++j) {
        float sj = s[j];
        rank += (sj > my) || (sj == my && j < i);
    }
    int k1 = rank < KP1;
    __syncthreads();
    // ---- top-k2 restricted to k1 set ----
    float my2 = k1 ? sc2[g * NPG + i] : -INFINITY;
    s[i] = my2;
    __syncthreads();
    rank = 0;
    for (int j = 0; j < NPG; ++j) {
        float sj = s[j];
        rank += (sj > my2) || (sj == my2 && j < i);
    }
    keep[i] = (unsigned char)(k1 && rank < KP2);
    __syncthreads();

    // ---- masked mean, float4: thread = (rowgroup r, ch4 c4) ----
    const int r = i >> 6, c4 = i & 63;
    float4 acc = make_float4(0.0f, 0.0f, 0.0f, 0.0f);
    const float4* f4 = (const float4*)(feat + (size_t)g * NPG * CC);
    for (int j = r; j < NPG; j += 8) {
        if (keep[j]) {
            float4 v = f4[j * 64 + c4];
            acc.x += v.x; acc.y += v.y; acc.z += v.z; acc.w += v.w;
        }
    }
    vbuf[r][c4 * 4 + 0] = acc.x;
    vbuf[r][c4 * 4 + 1] = acc.y;
    vbuf[r][c4 * 4 + 2] = acc.z;
    vbuf[r][c4 * 4 + 3] = acc.w;
    __syncthreads();
    if (i < CC) {
        float t = 0.0f;
#pragma unroll
        for (int q = 0; q < 8; ++q) t += vbuf[q][i];
        v0[i] = t * (1.0f / KP2);
    }
    __syncthreads();

    // ---- u = relu(v0 @ Wc + bc), split j-sum 8 ways ----
    {
        const int q = i >> 6, cth = i & 63;
        float p = 0.0f;
        for (int j = q * 32; j < q * 32 + 32; ++j)
            p = fmaf(v0[j], Wc[j * 64 + cth], p);
        part[q][cth] = p;
    }
    __syncthreads();
    if (i < 64) {
        float u = bc[i];
#pragma unroll
        for (int q = 0; q < 8; ++q) u += part[q][i];
        v2[i] = fmaxf(u, 0.0f);
    }
    __syncthreads();
    if (i < 2) {
        float o = c2b[i];
        for (int j = 0; j < 64; ++j) o = fmaf(v2[j], c2w[j * 2 + i], o);
        s[i] = o;
    }
    __syncthreads();
    if (i == 0) {
        float a = s[0], bq = s[1];
        float mx = fmaxf(a, bq);
        float lse = mx + logf(expf(a - mx) + expf(bq - mx));
        out[g * 2 + 0] = a - lse;
        out[g * 2 + 1] = bq - lse;
    }
}

// ---------------- launcher ----------------
extern "C" void kernel_launch(void* const* d_in, const int* in_sizes, int n_in,
                              void* d_out, int out_size, void* d_ws, size_t ws_size,
                              hipStream_t stream) {
    const float* x      = (const float*)d_in[0];
    const int*   ei     = (const int*)d_in[1];
    const int*   src    = ei;
    const int*   dst    = ei + EG;
    const float* W1     = (const float*)d_in[3];
    const float* a_src1 = (const float*)d_in[4];
    const float* a_dst1 = (const float*)d_in[5];
    const float* b1     = (const float*)d_in[6];
    const float* W2     = (const float*)d_in[7];
    const float* a_src2 = (const float*)d_in[8];
    const float* a_dst2 = (const float*)d_in[9];
    const float* b2     = (const float*)d_in[10];
    const float* p1_sw  = (const float*)d_in[11];
    const float* p1_sb  = (const float*)d_in[12];
    const float* p1_tw  = (const float*)d_in[13];
    const float* p1_tb  = (const float*)d_in[14];
    const float* p2_sw  = (const float*)d_in[15];
    const float* p2_sb  = (const float*)d_in[16];
    const float* p2_tw  = (const float*)d_in[17];
    const float* p2_tb  = (const float*)d_in[18];
    const float* c1w    = (const float*)d_in[19];
    const float* c1b    = (const float*)d_in[20];
    const float* c2w    = (const float*)d_in[21];
    const float* c2b    = (const float*)d_in[22];
    float* out = (float*)d_out;

    // workspace layout (floats)
    float* ws   = (float*)d_ws;
    float* z    = ws;                          // N*C
    float* feat = z + (size_t)NN * CC;         // N*C
    float* es   = feat + (size_t)NN * CC;      // N*H
    float* ed   = es + NN * HH;                // N*H
    int*   cnt  = (int*)(ed + NN * HH);        // N
    int*   rowp = cnt + NN;                    // N+1
    int*   cur  = rowp + NN + 1;               // N
    int*   esrc = cur + NN;                    // E
    float* sc1  = (float*)(esrc + EG);         // N
    float* sc2  = sc1 + NN;                    // N
    float* w12  = sc2 + NN;                    // C
    float* b12  = w12 + CC;                    // 1 (padded to 64)
    float* T    = b12 + 64;                    // 256*64
    float* Wc   = T + CC * 64;                 // 256*64
    float* bc2  = Wc + CC * 64;                // 64
    float* bcv  = bc2 + 64;                    // 64

    // ---- prep (cnt zero + w12 + T + bc2) and CSR build ----
    prep<<<194, 256, 0, stream>>>(cnt, p1_tw, p2_sw, p1_tb, p2_sb, w12, b12,
                                  p2_tw, c1w, p2_tb, T, bc2);
    csr_hist<<<(EG + 255) / 256, 256, 0, stream>>>(dst, cnt);
    csr_scan<<<1, 1024, 0, stream>>>(cnt, rowp, cur);
    csr_scatter<<<(EG + 255) / 256, 256, 0, stream>>>(src, dst, cur, esrc);
    fold_W<<<65, 256, 0, stream>>>(p1_tw, T, p1_tb, bc2, c1b, Wc, bcv);

    dim3 gemm_grid(NN / 128, CC / 64);

    // ---- GAT layer 1 ----
    gemm_fp32_attn<<<gemm_grid, 256, 0, stream>>>(x, W1, z, FIN,
                                                  a_src1, a_dst1, es, ed);
    gat_edge<<<NN / 4, 256, 0, stream>>>(z, rowp, esrc, es, ed, b1, feat,
                                         nullptr, nullptr, nullptr, nullptr,
                                         nullptr, nullptr);

    // ---- GAT layer 2 (pooling scores fused into epilogue) ----
    gemm_fp32_attn<<<gemm_grid, 256, 0, stream>>>(feat, W2, z, CC,
                                                  a_src2, a_dst2, es, ed);
    gat_edge<<<NN / 4, 256, 0, stream>>>(z, rowp, esrc, es, ed, b2, feat,
                                         p1_sw, p1_sb, w12, b12, sc1, sc2);

    // ---- fused pooling + folded head ----
    pool_head<<<BG, 512, 0, stream>>>(feat, sc1, sc2, Wc, bcv, c2w, c2b, out);
}